// Round 8
// baseline (3467.980 us; speedup 1.0000x reference)
//
#include <hip/hip_runtime.h>

#define Bq 8
#define Tq 2048
#define Dq 512

typedef const __attribute__((address_space(1))) void* gas_t;
typedef __attribute__((address_space(3))) void* las_t;

// One wave: DMA 1KB (64 lanes x 16B) global -> LDS. Per-lane global addr,
// wave-uniform LDS base. No VGPR defs; tracked only by the issuing wave's vmcnt.
__device__ __forceinline__ void dma1k(const float* g_lane, float* l_base) {
  __builtin_amdgcn_global_load_lds((gas_t)g_lane, (las_t)l_base, 16, 0, 0);
}

// DPP wave(64) sum, broadcast via readlane(63) -> SGPR.
template <int CTRL>
__device__ __forceinline__ float dppadd(float v) {
  int r = __builtin_amdgcn_update_dpp(0, __float_as_int(v), CTRL, 0xF, 0xF, true);
  return v + __int_as_float(r);
}
__device__ __forceinline__ float wave_sum_bcast(float v) {
  v = dppadd<0x111>(v);  // row_shr:1
  v = dppadd<0x112>(v);  // row_shr:2
  v = dppadd<0x114>(v);  // row_shr:4
  v = dppadd<0x118>(v);  // row_shr:8
  v = dppadd<0x142>(v);  // row_bcast:15
  v = dppadd<0x143>(v);  // row_bcast:31
  return __int_as_float(__builtin_amdgcn_readlane(__float_as_int(v), 63));
}

__device__ __forceinline__ float dot8(const float4& xa, const float4& xb,
                                      const float4& ya, const float4& yb) {
  float s = xa.x * ya.x;
  s = fmaf(xa.y, ya.y, s); s = fmaf(xa.z, ya.z, s); s = fmaf(xa.w, ya.w, s);
  s = fmaf(xb.x, yb.x, s); s = fmaf(xb.y, yb.y, s);
  s = fmaf(xb.z, yb.z, s); s = fmaf(xb.w, yb.w, s);
  return s;
}

#define WSUM4(dst, arr)                                                        \
  dst.x = q0 * arr[0].x + q1 * arr[1].x + q2 * arr[2].x + q3 * arr[3].x +      \
          q4 * arr[4].x;                                                       \
  dst.y = q0 * arr[0].y + q1 * arr[1].y + q2 * arr[2].y + q3 * arr[3].y +      \
          q4 * arr[4].y;                                                       \
  dst.z = q0 * arr[0].z + q1 * arr[1].z + q2 * arr[2].z + q3 * arr[3].z +      \
          q4 * arr[4].z;                                                       \
  dst.w = q0 * arr[0].w + q1 * arr[1].w + q2 * arr[2].w + q3 * arr[3].w +      \
          q4 * arr[4].w;

// LDS ring layout (float offsets): O 8 slots, G 8 slots, Pm 4, Pg 4 (2KB rows)
#define RING_O  0
#define RING_G  4096
#define RING_PM 8192
#define RING_PG 10240
// flags[0..7] = producer progress (O_e,O_o,G_e,G_o,Pm_e,Pm_o,Pg_e,Pg_o):
//   fl[i] = r means "rows of my parity <= r are RESIDENT in LDS".
// flags[8]  = consumer progress ct ("done reading step ct").
// "rows <= X resident" <=> pair-min(prog_even,prog_odd) >= X-1 (for X>=1).

__device__ __forceinline__ int imin2(int a, int b) { return a < b ? a : b; }

__device__ __forceinline__ void wait_rows(volatile int* fl, int needOG, int needPP,
                                          int& cOG, int& cPP) {
  if (cOG >= needOG && cPP >= needPP) return;
  for (;;) {
    int a0 = fl[0], a1 = fl[1], a2 = fl[2], a3 = fl[3];
    int b0 = fl[4], b1 = fl[5], b2 = fl[6], b3 = fl[7];
    int m1 = imin2(imin2(a0, a1), imin2(a2, a3));
    int m2 = imin2(imin2(b0, b1), imin2(b2, b3));
    if (m1 >= needOG && m2 >= needPP) { cOG = m1; cPP = m2; return; }
    __builtin_amdgcn_s_sleep(1);
  }
}

// ---------------------------------------------------------------------------
// Consumer step: no global loads, no vmcnt, no barrier. Reads window rows
// rb..rb+4 (O,G) and row t (Pm,Pg) from LDS rings, computes the recurrence,
// stores row t, publishes ct=t. Edge-invalid window entries are masked (score
// forced to exact 0 as in the reference's zero-padded rows; they keep exp(0)
// in the softmax denominator; stale slots hold finite reals -> 0*x safe).
// OSLOT: 4-deep output register rotation so compiler WAR waits on store
// sources reference ~4-step-old stores (non-blocking).
// ---------------------------------------------------------------------------
template <int OSLOT>
__device__ __forceinline__ void cstep(
    int t, int lane, volatile int* fl, const float* ring, float* __restrict__ po,
    int& cOG, int& cPP, float4& stA, float4& stB,
    float4& oA0, float4& oB0, float4& oA1, float4& oB1,
    float4& oA2, float4& oB2, float4& oA3, float4& oB3) {
  // flow control: O/G rows <= min(t+2,2047) resident, Pm/Pg row t resident
  int needOG = imin2(t + 2, Tq - 1) - 1;
  wait_rows(fl, needOG, t - 1, cOG, cPP);
  __builtin_amdgcn_sched_barrier(0);  // no data read hoists above the check

  int rb = t - 2; if (rb < 0) rb = 0;
  int lo = lane * 4;
  float4 wA[5], wB[5], gA[5], gB[5];
#pragma unroll
  for (int j = 0; j < 5; j++) {
    int sl = (rb + j) & 7;
    const float* pw = ring + RING_O + sl * Dq + lo;
    wA[j] = *(const float4*)pw;
    wB[j] = *(const float4*)(pw + 256);
    const float* pv = ring + RING_G + sl * Dq + lo;
    gA[j] = *(const float4*)pv;
    gB[j] = *(const float4*)(pv + 256);
  }
  const float* ppm = ring + RING_PM + (t & 3) * Dq + lo;
  float4 pmA = *(const float4*)ppm, pmB = *(const float4*)(ppm + 256);
  const float* ppq = ring + RING_PG + (t & 3) * Dq + lo;
  float4 pqA = *(const float4*)ppq, pqB = *(const float4*)(ppq + 256);

  float m3 = (t == 0 || t == Tq - 1) ? 0.f : 1.f;
  float m4 = (t >= 2 && t <= Tq - 3) ? 1.f : 0.f;

  const float scale = 0.04419417382415922f;  // 1/sqrt(512)
  float s0 = wave_sum_bcast(dot8(stA, stB, wA[0], wB[0])) * scale;
  float s1 = wave_sum_bcast(dot8(stA, stB, wA[1], wB[1])) * scale;
  float s2 = wave_sum_bcast(dot8(stA, stB, wA[2], wB[2])) * scale;
  float s3 = wave_sum_bcast(dot8(stA, stB, wA[3], wB[3])) * (scale * m3);
  float s4 = wave_sum_bcast(dot8(stA, stB, wA[4], wB[4])) * (scale * m4);
  float mx = fmaxf(fmaxf(fmaxf(s0, s1), fmaxf(s2, s3)), s4);
  float e0 = __expf(s0 - mx), e1 = __expf(s1 - mx), e2 = __expf(s2 - mx);
  float e3 = __expf(s3 - mx), e4 = __expf(s4 - mx);
  float inv = __fdividef(1.0f, e0 + e1 + e2 + e3 + e4);
  float q0 = e0 * inv, q1 = e1 * inv, q2 = e2 * inv;
  float q3 = e3 * inv * m3, q4 = e4 * inv * m4;  // padded rows contribute 0

  float4 atA, atB, gsA, gsB;
  WSUM4(atA, wA); WSUM4(atB, wB); WSUM4(gsA, gA); WSUM4(gsB, gB);
  float4 otA, otB;
  otA.x = fmaf(atA.x, __fdividef(1.f, 1.f + __expf(-(pqA.x + gsA.x))), pmA.x);
  otA.y = fmaf(atA.y, __fdividef(1.f, 1.f + __expf(-(pqA.y + gsA.y))), pmA.y);
  otA.z = fmaf(atA.z, __fdividef(1.f, 1.f + __expf(-(pqA.z + gsA.z))), pmA.z);
  otA.w = fmaf(atA.w, __fdividef(1.f, 1.f + __expf(-(pqA.w + gsA.w))), pmA.w);
  otB.x = fmaf(atB.x, __fdividef(1.f, 1.f + __expf(-(pqB.x + gsB.x))), pmB.x);
  otB.y = fmaf(atB.y, __fdividef(1.f, 1.f + __expf(-(pqB.y + gsB.y))), pmB.y);
  otB.z = fmaf(atB.z, __fdividef(1.f, 1.f + __expf(-(pqB.z + gsB.z))), pmB.z);
  otB.w = fmaf(atB.w, __fdividef(1.f, 1.f + __expf(-(pqB.w + gsB.w))), pmB.w);
  stA = otA; stB = otB;

  float4& osA = (OSLOT == 0) ? oA0 : (OSLOT == 1) ? oA1 : (OSLOT == 2) ? oA2 : oA3;
  float4& osB = (OSLOT == 0) ? oB0 : (OSLOT == 1) ? oB1 : (OSLOT == 2) ? oB2 : oB3;
  osA = otA; osB = otB;
  float* dst = po + (size_t)t * Dq + lo;
  *reinterpret_cast<float4*>(dst) = osA;
  *reinterpret_cast<float4*>(dst + 256) = osB;

  __builtin_amdgcn_sched_barrier(0);  // publish strictly after this step's reads
  if (lane == 0) fl[8] = t;  // LDS ops are in-order per wave: reads already sampled
}

// ---------------------------------------------------------------------------
// Scan: one block per batch, 9 waves. Wave 0 = consumer (owns all 512 dims,
// 8/lane). Waves 1..8 = producers: stream s=(w-1)>>1 (0:O,1:G,2:Pm,3:Pg),
// parity p=(w-1)&1; each DMAs its parity's rows with a 2-row-deep private
// vmcnt pipeline. Credit throttle ONLY on actual overwrites (rn > mask) —
// first-lap issues are credit-free, which breaks the R7 deadlock cycle:
// consumer step t <- pub_O(<=t+2) <- issue(<=t+4) <- ct >= t-2 < t  (induction).
// ---------------------------------------------------------------------------
__global__ __launch_bounds__(576, 1) void scan_kernel(
    const float* __restrict__ O, const float* __restrict__ Gm,
    const float* __restrict__ Pg, const float* __restrict__ Pm,
    float* __restrict__ out) {
  __shared__ float ring[12288];  // 48 KiB rings
  __shared__ int flags[16];

  int b = blockIdx.x;
  int tid = threadIdx.x;
  int w = tid >> 6;
  int lane = tid & 63;
  const float* ob  = O  + (size_t)b * Tq * Dq;
  const float* Gb  = Gm + (size_t)b * Tq * Dq;
  const float* pqb = Pg + (size_t)b * Tq * Dq;
  const float* pmb = Pm + (size_t)b * Tq * Dq;
  float* po = out + (size_t)b * Tq * Dq;

  if (tid < 16) flags[tid] = -1;
  __syncthreads();
  volatile int* fl = (volatile int*)flags;

  if (w == 0) {
    // ---- consumer ----
    int cOG = -2, cPP = -2;
    // Pre-wait: O/G rows <=5 resident (covers masked t=0/1 slot reads of rows
    // 0..4), Pm/Pg rows <=1 resident (row 0 used unmasked at t=0).
    // Reachable credit-free: needs issues of rows 6,7 (O/G, first lap) and
    // 2,3 (Pm/Pg, first lap) only.
    wait_rows(fl, 4, 0, cOG, cPP);
    __builtin_amdgcn_sched_barrier(0);

    float4 z = make_float4(0.f, 0.f, 0.f, 0.f);
    float4 stA = z, stB = z;
    float4 oA0 = z, oB0 = z, oA1 = z, oB1 = z;
    float4 oA2 = z, oB2 = z, oA3 = z, oB3 = z;
    for (int tb = 0; tb < Tq; tb += 4) {
      cstep<0>(tb + 0, lane, fl, (const float*)ring, po, cOG, cPP, stA, stB,
               oA0, oB0, oA1, oB1, oA2, oB2, oA3, oB3);
      cstep<1>(tb + 1, lane, fl, (const float*)ring, po, cOG, cPP, stA, stB,
               oA0, oB0, oA1, oB1, oA2, oB2, oA3, oB3);
      cstep<2>(tb + 2, lane, fl, (const float*)ring, po, cOG, cPP, stA, stB,
               oA0, oB0, oA1, oB1, oA2, oB2, oA3, oB3);
      cstep<3>(tb + 3, lane, fl, (const float*)ring, po, cOG, cPP, stA, stB,
               oA0, oB0, oA1, oB1, oA2, oB2, oA3, oB3);
    }
  } else {
    // ---- producer ----
    int s = (w - 1) >> 1, p = (w - 1) & 1;
    const float* src = (s == 0) ? ob : (s == 1) ? Gb : (s == 2) ? pmb : pqb;
    float* rb_ = (float*)ring +
                 ((s == 0) ? RING_O : (s == 1) ? RING_G : (s == 2) ? RING_PM : RING_PG);
    int mask = (s < 2) ? 7 : 3;  // ring slots - 1
    int RL   = (s < 2) ? 6 : 4;  // overwrite of slot (rn&mask) safe once ct >= rn-RL
    int pidx = s * 2 + p;

    int r = p;
    {
      const float* g = src + (size_t)r * Dq + lane * 4;
      float* l = rb_ + (r & mask) * Dq;
      dma1k(g, l); dma1k(g + 256, l + 256);
    }
    for (;;) {
      int rn = r + 2;
      if (rn < Tq) {
        if (rn > mask) {  // ONLY real overwrites need credit (fixes R7 deadlock)
          int thr = rn - RL;  // >= 0 here by construction
          while (fl[8] < thr) __builtin_amdgcn_s_sleep(1);
        }
        __builtin_amdgcn_sched_barrier(0);
        const float* g = src + (size_t)rn * Dq + lane * 4;
        float* l = rb_ + (rn & mask) * Dq;
        dma1k(g, l); dma1k(g + 256, l + 256);
        asm volatile("s_waitcnt vmcnt(2)" ::: "memory");  // row r landed in LDS
        if (lane == 0) fl[pidx] = r;
        r = rn;
      } else {
        asm volatile("s_waitcnt vmcnt(0)" ::: "memory");
        if (lane == 0) fl[pidx] = r;
        break;
      }
    }
  }
}

// ---------------------------------------------------------------------------
// Precompute GEMMs (unchanged): f32, 128x128x16 tiles, 8x8 microtile.
// mode 0: windowed-A GEMM (K=2560), n<512 -> PRE_mlp(+b_mlp) into Pm,
//         n>=512 -> PRE_gate(+b_gate). mode 1: G = O @ W_gate[:,2560:].T.
// ---------------------------------------------------------------------------
__global__ __launch_bounds__(256) void gemm_pre(
    const float* __restrict__ O, const float* __restrict__ Wm,
    const float* __restrict__ Wg, const float* __restrict__ bm,
    const float* __restrict__ bg, float* __restrict__ Pm,
    float* __restrict__ Pg, float* __restrict__ Gm, int mode) {
  const int BM = 128, BN = 128, BK = 16;
  __shared__ float As[BK][132];
  __shared__ float Bs[BK][132];

  int tidx = threadIdx.x;
  int bt0 = blockIdx.x * BM;
  int b = bt0 / Tq;
  int t0 = bt0 % Tq;
  int n0 = blockIdx.y * BN;
  int K = mode ? Dq : 5 * Dq;

  int tx = tidx % 16;
  int ty = tidx / 16;
  int lr = tidx >> 2;
  int lc = (tidx & 3) * 4;

  float acc[8][8];
#pragma unroll
  for (int i = 0; i < 8; i++)
#pragma unroll
    for (int j = 0; j < 8; j++) acc[i][j] = 0.f;

  for (int kb = 0; kb < K; kb += BK) {
#pragma unroll
    for (int h = 0; h < 2; h++) {
      int m = lr + h * 64;
      int t = t0 + m;
      float4 av;
      if (mode == 0) {
        int j = kb >> 9;
        int kcol = (kb & 511) + lc;
        int sh = 2 - t; if (sh < 0) sh = 0;
        int r = t - 2 + j + sh;
        int hi = t + 2; if (hi > Tq - 1) hi = Tq - 1;
        int lo2 = t - 2; if (lo2 < 0) lo2 = 0;
        int nv = hi - lo2 + 1;
        if (j < nv) {
          av = *reinterpret_cast<const float4*>(O + ((size_t)b * Tq + r) * Dq + kcol);
        } else {
          av = make_float4(0.f, 0.f, 0.f, 0.f);
        }
      } else {
        av = *reinterpret_cast<const float4*>(O + ((size_t)b * Tq + t) * Dq + kb + lc);
      }
      As[lc + 0][m] = av.x; As[lc + 1][m] = av.y;
      As[lc + 2][m] = av.z; As[lc + 3][m] = av.w;
    }
#pragma unroll
    for (int h = 0; h < 2; h++) {
      int n = lr + h * 64;
      int gn = n0 + n;
      const float* wrow;
      int col;
      if (mode == 0) {
        if (gn < 512) { wrow = Wm + (size_t)gn * 2560; col = kb + lc; }
        else          { wrow = Wg + (size_t)(gn - 512) * 3072; col = kb + lc; }
      } else {
        wrow = Wg + (size_t)gn * 3072; col = 2560 + kb + lc;
      }
      float4 bv = *reinterpret_cast<const float4*>(wrow + col);
      Bs[lc + 0][n] = bv.x; Bs[lc + 1][n] = bv.y;
      Bs[lc + 2][n] = bv.z; Bs[lc + 3][n] = bv.w;
    }
    __syncthreads();
#pragma unroll
    for (int kk = 0; kk < BK; kk++) {
      float a[8], bb[8];
      float4 a0 = *reinterpret_cast<float4*>(&As[kk][ty * 8]);
      float4 a1 = *reinterpret_cast<float4*>(&As[kk][ty * 8 + 4]);
      float4 b0 = *reinterpret_cast<float4*>(&Bs[kk][tx * 8]);
      float4 b1 = *reinterpret_cast<float4*>(&Bs[kk][tx * 8 + 4]);
      a[0]=a0.x; a[1]=a0.y; a[2]=a0.z; a[3]=a0.w; a[4]=a1.x; a[5]=a1.y; a[6]=a1.z; a[7]=a1.w;
      bb[0]=b0.x; bb[1]=b0.y; bb[2]=b0.z; bb[3]=b0.w; bb[4]=b1.x; bb[5]=b1.y; bb[6]=b1.z; bb[7]=b1.w;
#pragma unroll
      for (int i = 0; i < 8; i++)
#pragma unroll
        for (int j = 0; j < 8; j++) acc[i][j] = fmaf(a[i], bb[j], acc[i][j]);
    }
    __syncthreads();
  }

  int gn = n0 + tx * 8;
  float bias[8];
  float* dstbase;
  int coloff;
  if (mode == 0) {
    if (gn < 512) {
#pragma unroll
      for (int j = 0; j < 8; j++) bias[j] = bm[gn + j];
      dstbase = Pm; coloff = gn;
    } else {
#pragma unroll
      for (int j = 0; j < 8; j++) bias[j] = bg[gn - 512 + j];
      dstbase = Pg; coloff = gn - 512;
    }
  } else {
#pragma unroll
    for (int j = 0; j < 8; j++) bias[j] = 0.f;
    dstbase = Gm; coloff = gn;
  }
#pragma unroll
  for (int i = 0; i < 8; i++) {
    int bt = bt0 + ty * 8 + i;
    float4 v0 = make_float4(acc[i][0] + bias[0], acc[i][1] + bias[1],
                            acc[i][2] + bias[2], acc[i][3] + bias[3]);
    float4 v1 = make_float4(acc[i][4] + bias[4], acc[i][5] + bias[5],
                            acc[i][6] + bias[6], acc[i][7] + bias[7]);
    float4* d = reinterpret_cast<float4*>(dstbase + (size_t)bt * Dq + coloff);
    d[0] = v0;
    d[1] = v1;
  }
}

extern "C" void kernel_launch(void* const* d_in, const int* in_sizes, int n_in,
                              void* d_out, int out_size, void* d_ws, size_t ws_size,
                              hipStream_t stream) {
  const float* O  = (const float*)d_in[0];  // outputs [8,2048,512]
  const float* Wm = (const float*)d_in[1];  // W_mlp [512,2560]
  const float* bm = (const float*)d_in[2];  // b_mlp [512]
  const float* Wg = (const float*)d_in[3];  // W_gate [512,3072]
  const float* bg = (const float*)d_in[4];  // b_gate [512]
  float* out = (float*)d_out;               // [8,2048,512]

  const size_t NTOT = (size_t)Bq * Tq * Dq;  // 8.39M elements
  float* Pg = (float*)d_ws;                  // PRE_gate [8,2048,512]
  float* Gm = Pg + NTOT;                     // G        [8,2048,512]
  bool sep = ws_size >= (size_t)3 * NTOT * sizeof(float);
  float* Pm = sep ? (Gm + NTOT) : out;       // PRE_mlp (sep buffer if ws allows)

  gemm_pre<<<dim3(128, 8), dim3(256), 0, stream>>>(O, Wm, Wg, bm, bg, Pm, Pg, Gm, 0);
  gemm_pre<<<dim3(128, 4), dim3(256), 0, stream>>>(O, Wm, Wg, bm, bg, Pm, Pg, Gm, 1);

  scan_kernel<<<dim3(Bq), dim3(576), 0, stream>>>(O, Gm, Pg, Pm, out);
}

// Round 9
// 2995.966 us; speedup vs baseline: 1.1575x; 1.1575x over previous
//
#include <hip/hip_runtime.h>

#define Bq 8
#define Tq 2048
#define Dq 512

typedef const __attribute__((address_space(1))) void* gas_t;
typedef __attribute__((address_space(3))) void* las_t;

// Ring layout in floats: 4 streams x 16 slots x 512 floats (2KB rows)
#define RING_O  0
#define RING_G  8192
#define RING_PM 16384
#define RING_PG 24576
// flags[0..3] = per-stream resident watermark ("rows <= r are in LDS")
// flags[8]    = consumer progress ct ("done with step ct")

// One wave: DMA 1KB (64 lanes x 16B) global -> LDS. Per-lane global addr,
// wave-uniform LDS base. No VGPR defs; tracked only by issuing wave's vmcnt.
__device__ __forceinline__ void dma1k(const float* g_lane, float* l_base) {
  __builtin_amdgcn_global_load_lds((gas_t)g_lane, (las_t)l_base, 16, 0, 0);
}

// DPP wave(64) sum, broadcast via readlane(63) -> SGPR.
template <int CTRL>
__device__ __forceinline__ float dppadd(float v) {
  int r = __builtin_amdgcn_update_dpp(0, __float_as_int(v), CTRL, 0xF, 0xF, true);
  return v + __int_as_float(r);
}
__device__ __forceinline__ float wave_sum_bcast(float v) {
  v = dppadd<0x111>(v);  // row_shr:1
  v = dppadd<0x112>(v);  // row_shr:2
  v = dppadd<0x114>(v);  // row_shr:4
  v = dppadd<0x118>(v);  // row_shr:8
  v = dppadd<0x142>(v);  // row_bcast:15
  v = dppadd<0x143>(v);  // row_bcast:31
  return __int_as_float(__builtin_amdgcn_readlane(__float_as_int(v), 63));
}

__device__ __forceinline__ float dot8(const float4& xa, const float4& xb,
                                      const float4& ya, const float4& yb) {
  float s = xa.x * ya.x;
  s = fmaf(xa.y, ya.y, s); s = fmaf(xa.z, ya.z, s); s = fmaf(xa.w, ya.w, s);
  s = fmaf(xb.x, yb.x, s); s = fmaf(xb.y, yb.y, s);
  s = fmaf(xb.z, yb.z, s); s = fmaf(xb.w, yb.w, s);
  return s;
}

__device__ __forceinline__ float4 wsum5(
    float q0, float q1, float q2, float q3, float q4,
    const float4& a0, const float4& a1, const float4& a2,
    const float4& a3, const float4& a4) {
  float4 r;
  r.x = q0*a0.x + q1*a1.x + q2*a2.x + q3*a3.x + q4*a4.x;
  r.y = q0*a0.y + q1*a1.y + q2*a2.y + q3*a3.y + q4*a4.y;
  r.z = q0*a0.z + q1*a1.z + q2*a2.z + q3*a3.z + q4*a4.z;
  r.w = q0*a0.w + q1*a1.w + q2*a2.w + q3*a3.w + q4*a4.w;
  return r;
}

// ---------------------------------------------------------------------------
// Consumer step (single wave, lane owns 8 dims: lane*4..+4 and +256..).
// Window rows t-2..t+2 of O,G live in a 6-slot REGISTER window (static slots
// S0..S4 = (row)%6); per step we LDS-read only the new row rl=min(t+3,2047)
// into slot SL (consumed next step) plus Pm/Pg row t. Flow control via cached
// producer watermarks — with ~8 rows of producer slack a real poll happens
// only every ~6 steps. Edge-invalid window entries masked to score exactly 0
// (matching the reference's zero-padded rows; they keep exp(0) in the softmax
// denominator; stale slot data is finite so 0*x is safe). OS: 6-deep output
// register rotation so store-WAR waits reference 6-step-old stores (no-ops).
// ---------------------------------------------------------------------------
template <int S0, int S1, int S2, int S3, int S4, int SL, int OS>
__device__ __forceinline__ void cstep(
    int t, int lane, volatile int* fl, const float* ring, float* __restrict__ po,
    int& cOG, int& cPP,
    float4 (&wA)[6], float4 (&wB)[6], float4 (&gA)[6], float4 (&gB)[6],
    float4 (&oA)[6], float4 (&oB)[6], float4& stA, float4& stB) {
  int needOG = t + 3; if (needOG > Tq - 1) needOG = Tq - 1;
  if (cOG < needOG || cPP < t) {
    int it = 0;
    for (;;) {
      int f0 = fl[0], f1 = fl[1], f2 = fl[2], f3 = fl[3];
      int mOG = f0 < f1 ? f0 : f1;
      int mPP = f2 < f3 ? f2 : f3;
      if ((mOG >= needOG && mPP >= t) || ++it > (1 << 22)) {
        cOG = mOG; cPP = mPP; break;  // bound: turn bugs into absmax fail
      }
      __builtin_amdgcn_s_sleep(1);
    }
    if (cOG < needOG) cOG = needOG;  // after bound break, proceed anyway
    if (cPP < t) cPP = t;
  }
  __builtin_amdgcn_sched_barrier(0);  // no data read hoists above the check

  int lo = lane * 4;
  int rl = needOG;  // min(t+3, Tq-1)
  {
    const float* pw = ring + RING_O + (rl & 15) * Dq + lo;
    wA[SL] = *(const float4*)pw;
    wB[SL] = *(const float4*)(pw + 256);
    const float* pv = ring + RING_G + (rl & 15) * Dq + lo;
    gA[SL] = *(const float4*)pv;
    gB[SL] = *(const float4*)(pv + 256);
  }
  const float* ppm = ring + RING_PM + (t & 15) * Dq + lo;
  float4 pmA = *(const float4*)ppm, pmB = *(const float4*)(ppm + 256);
  const float* ppq = ring + RING_PG + (t & 15) * Dq + lo;
  float4 pqA = *(const float4*)ppq, pqB = *(const float4*)(ppq + 256);

  float m3 = (t == 0 || t == Tq - 1) ? 0.f : 1.f;
  float m4 = (t >= 2 && t <= Tq - 3) ? 1.f : 0.f;

  const float scale = 0.04419417382415922f;  // 1/sqrt(512)
  float s0 = wave_sum_bcast(dot8(stA, stB, wA[S0], wB[S0])) * scale;
  float s1 = wave_sum_bcast(dot8(stA, stB, wA[S1], wB[S1])) * scale;
  float s2 = wave_sum_bcast(dot8(stA, stB, wA[S2], wB[S2])) * scale;
  float s3 = wave_sum_bcast(dot8(stA, stB, wA[S3], wB[S3])) * (scale * m3);
  float s4 = wave_sum_bcast(dot8(stA, stB, wA[S4], wB[S4])) * (scale * m4);
  float mx = fmaxf(fmaxf(fmaxf(s0, s1), fmaxf(s2, s3)), s4);
  float e0 = __expf(s0 - mx), e1 = __expf(s1 - mx), e2 = __expf(s2 - mx);
  float e3 = __expf(s3 - mx), e4 = __expf(s4 - mx);
  float inv = __fdividef(1.0f, e0 + e1 + e2 + e3 + e4);
  float q0 = e0 * inv, q1 = e1 * inv, q2 = e2 * inv;
  float q3 = e3 * inv * m3, q4 = e4 * inv * m4;  // padded rows contribute 0

  float4 atA = wsum5(q0,q1,q2,q3,q4, wA[S0],wA[S1],wA[S2],wA[S3],wA[S4]);
  float4 atB = wsum5(q0,q1,q2,q3,q4, wB[S0],wB[S1],wB[S2],wB[S3],wB[S4]);
  float4 gsA = wsum5(q0,q1,q2,q3,q4, gA[S0],gA[S1],gA[S2],gA[S3],gA[S4]);
  float4 gsB = wsum5(q0,q1,q2,q3,q4, gB[S0],gB[S1],gB[S2],gB[S3],gB[S4]);

  float4 otA, otB;
  otA.x = fmaf(atA.x, __fdividef(1.f, 1.f + __expf(-(pqA.x + gsA.x))), pmA.x);
  otA.y = fmaf(atA.y, __fdividef(1.f, 1.f + __expf(-(pqA.y + gsA.y))), pmA.y);
  otA.z = fmaf(atA.z, __fdividef(1.f, 1.f + __expf(-(pqA.z + gsA.z))), pmA.z);
  otA.w = fmaf(atA.w, __fdividef(1.f, 1.f + __expf(-(pqA.w + gsA.w))), pmA.w);
  otB.x = fmaf(atB.x, __fdividef(1.f, 1.f + __expf(-(pqB.x + gsB.x))), pmB.x);
  otB.y = fmaf(atB.y, __fdividef(1.f, 1.f + __expf(-(pqB.y + gsB.y))), pmB.y);
  otB.z = fmaf(atB.z, __fdividef(1.f, 1.f + __expf(-(pqB.z + gsB.z))), pmB.z);
  otB.w = fmaf(atB.w, __fdividef(1.f, 1.f + __expf(-(pqB.w + gsB.w))), pmB.w);
  stA = otA; stB = otB;

  oA[OS] = otA; oB[OS] = otB;
  float* dst = po + (size_t)t * Dq + lo;
  *reinterpret_cast<float4*>(dst) = oA[OS];
  *reinterpret_cast<float4*>(dst + 256) = oB[OS];

  __builtin_amdgcn_sched_barrier(0);  // publish strictly after this step's reads
  if (lane == 0) fl[8] = t;
}

// ---------------------------------------------------------------------------
// Scan: one block per batch, 5 waves. Wave 0 = consumer. Waves 1..4 =
// producers, one per stream (0:O,1:G,2:Pm,3:Pg), 6-row-deep vmcnt pipeline:
// issue row r, s_waitcnt vmcnt(10) (retires rows <= r-5), publish r-5.
// Credit: overwrites (r>=16) need ct >= r-14 (row r-16's last read is step
// r-14). First lap credit-free. Induction: step t needs fl_OG >= t+3
// <- issue(t+8) <- ct >= t-6 < t; fl_PP >= t <- issue(t+5) <- ct >= t-9 < t.
// ---------------------------------------------------------------------------
__global__ __launch_bounds__(320, 1) void scan_kernel(
    const float* __restrict__ O, const float* __restrict__ Gm,
    const float* __restrict__ Pg, const float* __restrict__ Pm,
    float* __restrict__ out) {
  __shared__ float ring[32768];  // 128 KiB: 4 streams x 16 slots x 2KB
  __shared__ int flags[16];

  int b = blockIdx.x;
  int tid = threadIdx.x;
  int w = tid >> 6;
  int lane = tid & 63;
  const float* ob  = O  + (size_t)b * Tq * Dq;
  const float* Gb  = Gm + (size_t)b * Tq * Dq;
  const float* pqb = Pg + (size_t)b * Tq * Dq;
  const float* pmb = Pm + (size_t)b * Tq * Dq;
  float* po = out + (size_t)b * Tq * Dq;

  if (tid < 16) flags[tid] = -1;
  __syncthreads();
  volatile int* fl = (volatile int*)flags;

  if (w == 0) {
    // ---------------- consumer ----------------
    int cOG = -1, cPP = -1;
    {  // pre-wait: O/G rows <= 2 resident (prologue reads rows 0..2)
      int it = 0;
      for (;;) {
        int f0 = fl[0], f1 = fl[1];
        int m = f0 < f1 ? f0 : f1;
        if (m >= 2 || ++it > (1 << 22)) break;
        __builtin_amdgcn_s_sleep(1);
      }
    }
    __builtin_amdgcn_sched_barrier(0);

    float4 z = make_float4(0.f, 0.f, 0.f, 0.f);
    float4 wA[6], wB[6], gA[6], gB[6], oA[6], oB[6];
#pragma unroll
    for (int s = 0; s < 6; s++) {
      wA[s] = z; wB[s] = z; gA[s] = z; gB[s] = z; oA[s] = z; oB[s] = z;
    }
    float4 stA = z, stB = z;
    int lo = lane * 4;
    const float* rg = (const float*)ring;
#pragma unroll
    for (int r = 0; r < 3; r++) {  // rows 0..2 -> slots 0..2
      const float* pw = rg + RING_O + r * Dq + lo;
      wA[r] = *(const float4*)pw;
      wB[r] = *(const float4*)(pw + 256);
      const float* pv = rg + RING_G + r * Dq + lo;
      gA[r] = *(const float4*)pv;
      gB[r] = *(const float4*)(pv + 256);
    }

    // slot(row r) = r % 6; at step t: S_j = (max(0,t-2)+j)%6, SL = (t+3)%6.
    cstep<0,1,2,3,4, 3, 0>(0, lane, fl, rg, po, cOG, cPP, wA,wB,gA,gB,oA,oB, stA,stB);
    cstep<0,1,2,3,4, 4, 1>(1, lane, fl, rg, po, cOG, cPP, wA,wB,gA,gB,oA,oB, stA,stB);
    cstep<0,1,2,3,4, 5, 2>(2, lane, fl, rg, po, cOG, cPP, wA,wB,gA,gB,oA,oB, stA,stB);
    cstep<1,2,3,4,5, 0, 3>(3, lane, fl, rg, po, cOG, cPP, wA,wB,gA,gB,oA,oB, stA,stB);
    for (int tb = 4; tb <= 2038; tb += 6) {  // t = 4..2043
      cstep<2,3,4,5,0, 1, 0>(tb+0, lane, fl, rg, po, cOG, cPP, wA,wB,gA,gB,oA,oB, stA,stB);
      cstep<3,4,5,0,1, 2, 1>(tb+1, lane, fl, rg, po, cOG, cPP, wA,wB,gA,gB,oA,oB, stA,stB);
      cstep<4,5,0,1,2, 3, 2>(tb+2, lane, fl, rg, po, cOG, cPP, wA,wB,gA,gB,oA,oB, stA,stB);
      cstep<5,0,1,2,3, 4, 3>(tb+3, lane, fl, rg, po, cOG, cPP, wA,wB,gA,gB,oA,oB, stA,stB);
      cstep<0,1,2,3,4, 5, 4>(tb+4, lane, fl, rg, po, cOG, cPP, wA,wB,gA,gB,oA,oB, stA,stB);
      cstep<1,2,3,4,5, 0, 5>(tb+5, lane, fl, rg, po, cOG, cPP, wA,wB,gA,gB,oA,oB, stA,stB);
    }
    // tail t = 2044..2047 (phases 4,5,0,1 of the cycle)
    cstep<2,3,4,5,0, 1, 0>(2044, lane, fl, rg, po, cOG, cPP, wA,wB,gA,gB,oA,oB, stA,stB);
    cstep<3,4,5,0,1, 2, 1>(2045, lane, fl, rg, po, cOG, cPP, wA,wB,gA,gB,oA,oB, stA,stB);
    cstep<4,5,0,1,2, 3, 2>(2046, lane, fl, rg, po, cOG, cPP, wA,wB,gA,gB,oA,oB, stA,stB);
    cstep<5,0,1,2,3, 4, 3>(2047, lane, fl, rg, po, cOG, cPP, wA,wB,gA,gB,oA,oB, stA,stB);
  } else {
    // ---------------- producers ----------------
    int s = w - 1;
    const float* src = (s == 0) ? ob : (s == 1) ? Gb : (s == 2) ? pmb : pqb;
    float* rbase = (float*)ring + s * 8192;  // 16 slots x 512 floats

    // fill rows 0..7 (first lap, credit-free)
    for (int r = 0; r < 8; ++r) {
      const float* g = src + (size_t)r * Dq + lane * 4;
      float* l = rbase + (r & 15) * Dq;
      dma1k(g, l); dma1k(g + 256, l + 256);
    }
    for (int r = 8; r < Tq; ++r) {
      if (r >= 16) {  // overwrite of row r-16: safe once ct >= r-14
        int thr = r - 14;
        int it = 0;
        while (fl[8] < thr) {
          __builtin_amdgcn_s_sleep(1);
          if (++it > (1 << 22)) break;  // bound: bug -> absmax fail, not hang
        }
      }
      __builtin_amdgcn_sched_barrier(0);
      const float* g = src + (size_t)r * Dq + lane * 4;
      float* l = rbase + (r & 15) * Dq;
      dma1k(g, l); dma1k(g + 256, l + 256);
      asm volatile("s_waitcnt vmcnt(10)" ::: "memory");  // rows <= r-5 landed
      if (lane == 0) fl[s] = r - 5;
      __builtin_amdgcn_sched_barrier(0);
    }
    asm volatile("s_waitcnt vmcnt(0)" ::: "memory");
    if (lane == 0) fl[s] = Tq - 1;
  }
}

// ---------------------------------------------------------------------------
// Precompute GEMMs (unchanged): f32, 128x128x16 tiles, 8x8 microtile.
// mode 0: windowed-A GEMM (K=2560), n<512 -> PRE_mlp(+b_mlp) into Pm,
//         n>=512 -> PRE_gate(+b_gate). mode 1: G = O @ W_gate[:,2560:].T.
// ---------------------------------------------------------------------------
__global__ __launch_bounds__(256) void gemm_pre(
    const float* __restrict__ O, const float* __restrict__ Wm,
    const float* __restrict__ Wg, const float* __restrict__ bm,
    const float* __restrict__ bg, float* __restrict__ Pm,
    float* __restrict__ Pg, float* __restrict__ Gm, int mode) {
  const int BM = 128, BN = 128, BK = 16;
  __shared__ float As[BK][132];
  __shared__ float Bs[BK][132];

  int tidx = threadIdx.x;
  int bt0 = blockIdx.x * BM;
  int b = bt0 / Tq;
  int t0 = bt0 % Tq;
  int n0 = blockIdx.y * BN;
  int K = mode ? Dq : 5 * Dq;

  int tx = tidx % 16;
  int ty = tidx / 16;
  int lr = tidx >> 2;
  int lc = (tidx & 3) * 4;

  float acc[8][8];
#pragma unroll
  for (int i = 0; i < 8; i++)
#pragma unroll
    for (int j = 0; j < 8; j++) acc[i][j] = 0.f;

  for (int kb = 0; kb < K; kb += BK) {
#pragma unroll
    for (int h = 0; h < 2; h++) {
      int m = lr + h * 64;
      int t = t0 + m;
      float4 av;
      if (mode == 0) {
        int j = kb >> 9;
        int kcol = (kb & 511) + lc;
        int sh = 2 - t; if (sh < 0) sh = 0;
        int r = t - 2 + j + sh;
        int hi = t + 2; if (hi > Tq - 1) hi = Tq - 1;
        int lo2 = t - 2; if (lo2 < 0) lo2 = 0;
        int nv = hi - lo2 + 1;
        if (j < nv) {
          av = *reinterpret_cast<const float4*>(O + ((size_t)b * Tq + r) * Dq + kcol);
        } else {
          av = make_float4(0.f, 0.f, 0.f, 0.f);
        }
      } else {
        av = *reinterpret_cast<const float4*>(O + ((size_t)b * Tq + t) * Dq + kb + lc);
      }
      As[lc + 0][m] = av.x; As[lc + 1][m] = av.y;
      As[lc + 2][m] = av.z; As[lc + 3][m] = av.w;
    }
#pragma unroll
    for (int h = 0; h < 2; h++) {
      int n = lr + h * 64;
      int gn = n0 + n;
      const float* wrow;
      int col;
      if (mode == 0) {
        if (gn < 512) { wrow = Wm + (size_t)gn * 2560; col = kb + lc; }
        else          { wrow = Wg + (size_t)(gn - 512) * 3072; col = kb + lc; }
      } else {
        wrow = Wg + (size_t)gn * 3072; col = 2560 + kb + lc;
      }
      float4 bv = *reinterpret_cast<const float4*>(wrow + col);
      Bs[lc + 0][n] = bv.x; Bs[lc + 1][n] = bv.y;
      Bs[lc + 2][n] = bv.z; Bs[lc + 3][n] = bv.w;
    }
    __syncthreads();
#pragma unroll
    for (int kk = 0; kk < BK; kk++) {
      float a[8], bb[8];
      float4 a0 = *reinterpret_cast<float4*>(&As[kk][ty * 8]);
      float4 a1 = *reinterpret_cast<float4*>(&As[kk][ty * 8 + 4]);
      float4 b0 = *reinterpret_cast<float4*>(&Bs[kk][tx * 8]);
      float4 b1 = *reinterpret_cast<float4*>(&Bs[kk][tx * 8 + 4]);
      a[0]=a0.x; a[1]=a0.y; a[2]=a0.z; a[3]=a0.w; a[4]=a1.x; a[5]=a1.y; a[6]=a1.z; a[7]=a1.w;
      bb[0]=b0.x; bb[1]=b0.y; bb[2]=b0.z; bb[3]=b0.w; bb[4]=b1.x; bb[5]=b1.y; bb[6]=b1.z; bb[7]=b1.w;
#pragma unroll
      for (int i = 0; i < 8; i++)
#pragma unroll
        for (int j = 0; j < 8; j++) acc[i][j] = fmaf(a[i], bb[j], acc[i][j]);
    }
    __syncthreads();
  }

  int gn = n0 + tx * 8;
  float bias[8];
  float* dstbase;
  int coloff;
  if (mode == 0) {
    if (gn < 512) {
#pragma unroll
      for (int j = 0; j < 8; j++) bias[j] = bm[gn + j];
      dstbase = Pm; coloff = gn;
    } else {
#pragma unroll
      for (int j = 0; j < 8; j++) bias[j] = bg[gn - 512 + j];
      dstbase = Pg; coloff = gn - 512;
    }
  } else {
#pragma unroll
    for (int j = 0; j < 8; j++) bias[j] = 0.f;
    dstbase = Gm; coloff = gn;
  }
#pragma unroll
  for (int i = 0; i < 8; i++) {
    int bt = bt0 + ty * 8 + i;
    float4 v0 = make_float4(acc[i][0] + bias[0], acc[i][1] + bias[1],
                            acc[i][2] + bias[2], acc[i][3] + bias[3]);
    float4 v1 = make_float4(acc[i][4] + bias[4], acc[i][5] + bias[5],
                            acc[i][6] + bias[6], acc[i][7] + bias[7]);
    float4* d = reinterpret_cast<float4*>(dstbase + (size_t)bt * Dq + coloff);
    d[0] = v0;
    d[1] = v1;
  }
}

extern "C" void kernel_launch(void* const* d_in, const int* in_sizes, int n_in,
                              void* d_out, int out_size, void* d_ws, size_t ws_size,
                              hipStream_t stream) {
  const float* O  = (const float*)d_in[0];  // outputs [8,2048,512]
  const float* Wm = (const float*)d_in[1];  // W_mlp [512,2560]
  const float* bm = (const float*)d_in[2];  // b_mlp [512]
  const float* Wg = (const float*)d_in[3];  // W_gate [512,3072]
  const float* bg = (const float*)d_in[4];  // b_gate [512]
  float* out = (float*)d_out;               // [8,2048,512]

  const size_t NTOT = (size_t)Bq * Tq * Dq;  // 8.39M elements
  float* Pg = (float*)d_ws;                  // PRE_gate [8,2048,512]
  float* Gm = Pg + NTOT;                     // G        [8,2048,512]
  bool sep = ws_size >= (size_t)3 * NTOT * sizeof(float);
  float* Pm = sep ? (Gm + NTOT) : out;       // PRE_mlp (sep buffer if ws allows)

  gemm_pre<<<dim3(128, 8), dim3(256), 0, stream>>>(O, Wm, Wg, bm, bg, Pm, Pg, Gm, 0);
  gemm_pre<<<dim3(128, 4), dim3(256), 0, stream>>>(O, Wm, Wg, bm, bg, Pm, Pg, Gm, 1);

  scan_kernel<<<dim3(Bq), dim3(320), 0, stream>>>(O, Gm, Pg, Pm, out);
}

// Round 12
// 2227.019 us; speedup vs baseline: 1.5572x; 1.3453x over previous
//
#include <hip/hip_runtime.h>

#define Bq 8
#define Tq 2048
#define Dq 512

typedef __attribute__((ext_vector_type(8))) _Float16 f16x8;  // 8 f16 = 4 VGPRs
typedef __attribute__((ext_vector_type(8))) short u16x8;
typedef __attribute__((ext_vector_type(4))) float f32x4;

// ---------------------------------------------------------------------------
// f32 -> (hi,lo) f16 split planes, with x*256 pre-scale so lo stays in f16
// normal range for N(0,1) activations and ~0.02-scale weights. x*256 is
// recovered by a 2^-16 scale in the GEMM epilogue.
// ---------------------------------------------------------------------------
__global__ __launch_bounds__(256) void cvt_f16split(
    const float* __restrict__ s, ushort* __restrict__ hi,
    ushort* __restrict__ lo, int n8) {
  int i = blockIdx.x * 256 + threadIdx.x;
  if (i >= n8) return;
  const float4* sp = reinterpret_cast<const float4*>(s) + i * 2;
  float4 a = sp[0], b = sp[1];
  float x[8] = {a.x, a.y, a.z, a.w, b.x, b.y, b.z, b.w};
  ushort h[8], l[8];
#pragma unroll
  for (int e = 0; e < 8; e++) {
    float xs = x[e] * 256.0f;
    _Float16 hh = (_Float16)xs;
    _Float16 ll = (_Float16)(xs - (float)hh);
    h[e] = *(ushort*)&hh;
    l[e] = *(ushort*)&ll;
  }
  *reinterpret_cast<u16x8*>(hi + (size_t)i * 8) = *reinterpret_cast<u16x8*>(h);
  *reinterpret_cast<u16x8*>(lo + (size_t)i * 8) = *reinterpret_cast<u16x8*>(l);
}

// ---------------------------------------------------------------------------
// Split-f16 MFMA GEMM (R10 direct-gather structure — validated by the R10/R11
// bit-identical-output experiment; bf16->f16split is the only change).
// Fragments (16B-contiguous along K):
//   A: row = l&15, k = (l>>4)*8+e ; B: col = l&15, k = (l>>4)*8+e
//   D: col = l&15, row = (l>>4)*4+reg   [guide m89/m91]
// Per K=32 step: acc += Ah*Bh + Al*Bh + Ah*Bl  (AlBl dropped, ~2^-22 rel).
// Epilogue scales by 2^-16 (undoes the two 2^8 pre-scales) and adds bias.
// MODE 0: PRE = windowflat @ {Wm | Wg[:, :2560]}^T + bias (K=2560; by<4->Pm,
//         else->Pg).  MODE 1: G = O @ Wg[:, 2560:]^T (K=512).
// ---------------------------------------------------------------------------
template <int MODE>
__global__ __launch_bounds__(256) void gemm_mfma(
    const ushort* __restrict__ Ohi, const ushort* __restrict__ Olo,
    const ushort* __restrict__ Wmh, const ushort* __restrict__ Wml,
    const ushort* __restrict__ Wgh, const ushort* __restrict__ Wgl,
    const float* __restrict__ bm, const float* __restrict__ bg,
    float* __restrict__ Pm, float* __restrict__ Pg, float* __restrict__ Gm) {
  int tid = threadIdx.x;
  int l = tid & 63, w = tid >> 6;
  int wm = w >> 1, wn = w & 1;
  int r16 = l & 15, kg = l >> 4;
  int bt0 = blockIdx.x * 128;
  int by = blockIdx.y;
  int gb = (bt0 / Tq) * Tq;   // batch base (tiles never cross batches)
  int t0 = bt0 % Tq;

  f32x4 acc[4][4] = {};
  const f16x8 zz = {0, 0, 0, 0, 0, 0, 0, 0};

  // ---- B plane pointers: 4 ni tiles, row-major weights, +32 elems/step ----
  const ushort* bph[4];
  const ushort* bpl[4];
  int ncol[4];
#pragma unroll
  for (int ni = 0; ni < 4; ni++) {
    int n_g = by * 128 + wn * 64 + ni * 16 + r16;
    ncol[ni] = n_g;
    size_t off;
    if (MODE == 1) {
      off = (size_t)n_g * 3072 + 2560 + kg * 8;
      bph[ni] = Wgh + off; bpl[ni] = Wgl + off;
    } else if (by < 4) {
      off = (size_t)n_g * 2560 + kg * 8;
      bph[ni] = Wmh + off; bpl[ni] = Wml + off;
    } else {
      off = (size_t)(n_g - 512) * 3072 + kg * 8;
      bph[ni] = Wgh + off; bpl[ni] = Wgl + off;
    }
  }

  if (MODE == 1) {
    const ushort *aph[4], *apl[4];
#pragma unroll
    for (int mi = 0; mi < 4; mi++) {
      size_t off = (size_t)(bt0 + wm * 64 + mi * 16 + r16) * Dq + kg * 8;
      aph[mi] = Ohi + off; apl[mi] = Olo + off;
    }
#pragma unroll 4
    for (int ks = 0; ks < 16; ks++) {
      f16x8 Ah[4], Al[4], Bh[4], Bl[4];
#pragma unroll
      for (int mi = 0; mi < 4; mi++) {
        Ah[mi] = *(const f16x8*)aph[mi]; aph[mi] += 32;
        Al[mi] = *(const f16x8*)apl[mi]; apl[mi] += 32;
      }
#pragma unroll
      for (int ni = 0; ni < 4; ni++) {
        Bh[ni] = *(const f16x8*)bph[ni]; bph[ni] += 32;
        Bl[ni] = *(const f16x8*)bpl[ni]; bpl[ni] += 32;
      }
#pragma unroll
      for (int mi = 0; mi < 4; mi++)
#pragma unroll
        for (int ni = 0; ni < 4; ni++) {
          acc[mi][ni] = __builtin_amdgcn_mfma_f32_16x16x32_f16(Ah[mi], Bh[ni], acc[mi][ni], 0, 0, 0);
          acc[mi][ni] = __builtin_amdgcn_mfma_f32_16x16x32_f16(Al[mi], Bh[ni], acc[mi][ni], 0, 0, 0);
          acc[mi][ni] = __builtin_amdgcn_mfma_f32_16x16x32_f16(Ah[mi], Bl[ni], acc[mi][ni], 0, 0, 0);
        }
    }
  } else {
    // ---- per-lane window rows + validity (logic identical to verified f32) ----
    int arow[4][5];
    uint vmask[4];
#pragma unroll
    for (int mi = 0; mi < 4; mi++) {
      int t = t0 + wm * 64 + mi * 16 + r16;
      int sh = 2 - t; if (sh < 0) sh = 0;
      int hi2 = t + 2; if (hi2 > Tq - 1) hi2 = Tq - 1;
      int lo2 = t - 2; if (lo2 < 0) lo2 = 0;
      int nv = hi2 - lo2 + 1;
      uint vm = 0;
#pragma unroll
      for (int j = 0; j < 5; j++) {
        int r = t - 2 + j + sh;
        if (r > Tq - 1) r = Tq - 1;
        arow[mi][j] = gb + r;
        if (j < nv) vm |= (1u << j);
      }
      vmask[mi] = vm;
    }
#pragma unroll
    for (int j = 0; j < 5; j++) {
      const ushort *aph[4], *apl[4];
      bool v[4];
#pragma unroll
      for (int mi = 0; mi < 4; mi++) {
        size_t off = (size_t)arow[mi][j] * Dq + kg * 8;
        aph[mi] = Ohi + off; apl[mi] = Olo + off;
        v[mi] = (vmask[mi] >> j) & 1u;
      }
#pragma unroll 4
      for (int ks = 0; ks < 16; ks++) {
        f16x8 Ah[4], Al[4], Bh[4], Bl[4];
#pragma unroll
        for (int mi = 0; mi < 4; mi++) {
          f16x8 th = *(const f16x8*)aph[mi]; aph[mi] += 32;
          f16x8 tl = *(const f16x8*)apl[mi]; apl[mi] += 32;
          Ah[mi] = v[mi] ? th : zz;
          Al[mi] = v[mi] ? tl : zz;
        }
#pragma unroll
        for (int ni = 0; ni < 4; ni++) {
          Bh[ni] = *(const f16x8*)bph[ni]; bph[ni] += 32;
          Bl[ni] = *(const f16x8*)bpl[ni]; bpl[ni] += 32;
        }
#pragma unroll
        for (int mi = 0; mi < 4; mi++)
#pragma unroll
          for (int ni = 0; ni < 4; ni++) {
            acc[mi][ni] = __builtin_amdgcn_mfma_f32_16x16x32_f16(Ah[mi], Bh[ni], acc[mi][ni], 0, 0, 0);
            acc[mi][ni] = __builtin_amdgcn_mfma_f32_16x16x32_f16(Al[mi], Bh[ni], acc[mi][ni], 0, 0, 0);
            acc[mi][ni] = __builtin_amdgcn_mfma_f32_16x16x32_f16(Ah[mi], Bl[ni], acc[mi][ni], 0, 0, 0);
          }
      }
    }
  }

  // ---- epilogue: 2^-16 scale + bias; C/D map col=l&15, row=(l>>4)*4+reg ----
  const float SC = 1.0f / 65536.0f;
  float* dst;
  const float* bias;
  if (MODE == 1) { dst = Gm; bias = nullptr; }
  else if (by < 4) { dst = Pm; bias = bm; }
  else { dst = Pg; bias = bg; }
#pragma unroll
  for (int ni = 0; ni < 4; ni++) {
    int oc = (MODE == 1) ? ncol[ni] : (by < 4 ? ncol[ni] : ncol[ni] - 512);
    float bi = bias ? bias[oc] : 0.f;
#pragma unroll
    for (int mi = 0; mi < 4; mi++) {
      int rowb = bt0 + wm * 64 + mi * 16 + kg * 4;
#pragma unroll
      for (int rr = 0; rr < 4; rr++) {
        dst[(size_t)(rowb + rr) * Dq + oc] = fmaf(acc[mi][ni][rr], SC, bi);
      }
    }
  }
}

// ===========================================================================
// Scan: R4 structure verbatim (best measured: 1742 us; correctness-proven).
// ===========================================================================
template <int CTRL>
__device__ __forceinline__ float dppadd(float v) {
  int r = __builtin_amdgcn_update_dpp(0, __float_as_int(v), CTRL, 0xF, 0xF, true);
  return v + __int_as_float(r);
}
__device__ __forceinline__ float wave_sum_bcast(float v) {
  v = dppadd<0x111>(v);
  v = dppadd<0x112>(v);
  v = dppadd<0x114>(v);
  v = dppadd<0x118>(v);
  v = dppadd<0x142>(v);
  v = dppadd<0x143>(v);
  return __int_as_float(__builtin_amdgcn_readlane(__float_as_int(v), 63));
}

__device__ __forceinline__ void load_row(const float* __restrict__ base, int r,
                                         int lane, float4& a, float4& b) {
  const float* p = base + (size_t)r * Dq + lane * 4;
  a = *reinterpret_cast<const float4*>(p);
  b = *reinterpret_cast<const float4*>(p + 256);
}

__device__ __forceinline__ float dot8(const float4& xa, const float4& xb,
                                      const float4& ya, const float4& yb) {
  float s = xa.x * ya.x;
  s = fmaf(xa.y, ya.y, s); s = fmaf(xa.z, ya.z, s); s = fmaf(xa.w, ya.w, s);
  s = fmaf(xb.x, yb.x, s); s = fmaf(xb.y, yb.y, s);
  s = fmaf(xb.z, yb.z, s); s = fmaf(xb.w, yb.w, s);
  return s;
}

__device__ __forceinline__ float4 gate_out(const float4& pm, const float4& pg,
                                           const float4& at, const float4& gs) {
  float4 o;
  o.x = fmaf(at.x, __fdividef(1.f, 1.f + __expf(-(pg.x + gs.x))), pm.x);
  o.y = fmaf(at.y, __fdividef(1.f, 1.f + __expf(-(pg.y + gs.y))), pm.y);
  o.z = fmaf(at.z, __fdividef(1.f, 1.f + __expf(-(pg.z + gs.z))), pm.z);
  o.w = fmaf(at.w, __fdividef(1.f, 1.f + __expf(-(pg.w + gs.w))), pm.w);
  return o;
}

#define WSUM4(dst, arr)                                                        \
  dst.x = q0 * arr[S0].x + q1 * arr[S1].x + q2 * arr[S2].x + q3 * arr[S3].x +  \
          q4 * arr[S4].x;                                                      \
  dst.y = q0 * arr[S0].y + q1 * arr[S1].y + q2 * arr[S2].y + q3 * arr[S3].y +  \
          q4 * arr[S4].y;                                                      \
  dst.z = q0 * arr[S0].z + q1 * arr[S1].z + q2 * arr[S2].z + q3 * arr[S3].z +  \
          q4 * arr[S4].z;                                                      \
  dst.w = q0 * arr[S0].w + q1 * arr[S1].w + q2 * arr[S2].w + q3 * arr[S3].w +  \
          q4 * arr[S4].w;

template <int S0, int S1, int S2, int S3, int S4, int SLOT, int SLW, bool FLUSH>
__device__ __forceinline__ void scan_step(
    int t, float m3, float m4,
    const float* __restrict__ ob, const float* __restrict__ Gb,
    const float* __restrict__ Pgb, const float* __restrict__ pmb,
    float* __restrict__ po,
    float4 (&owA)[8], float4 (&owB)[8], float4 (&gwA)[8], float4 (&gwB)[8],
    float4 (&pmA)[8], float4 (&pmB)[8], float4 (&pgA)[8], float4 (&pgB)[8],
    float4& stA, float4& stB, int lane, float (*outl)[Dq]) {
  int rw = t + 5; if (rw > Tq - 1) rw = Tq - 1;
  load_row(ob,  rw, lane, owA[SLW], owB[SLW]);
  load_row(Gb,  rw, lane, gwA[SLW], gwB[SLW]);
  load_row(pmb, rw, lane, pmA[SLW], pmB[SLW]);
  load_row(Pgb, rw, lane, pgA[SLW], pgB[SLW]);
  __builtin_amdgcn_sched_barrier(0);

  float s0 = dot8(stA, stB, owA[S0], owB[S0]);
  float s1 = dot8(stA, stB, owA[S1], owB[S1]);
  float s2 = dot8(stA, stB, owA[S2], owB[S2]);
  float s3 = dot8(stA, stB, owA[S3], owB[S3]);
  float s4 = dot8(stA, stB, owA[S4], owB[S4]);
  const float scale = 0.04419417382415922f;
  s0 = wave_sum_bcast(s0) * scale;
  s1 = wave_sum_bcast(s1) * scale;
  s2 = wave_sum_bcast(s2) * scale;
  s3 = wave_sum_bcast(s3) * (scale * m3);
  s4 = wave_sum_bcast(s4) * (scale * m4);

  float mx = fmaxf(fmaxf(fmaxf(s0, s1), fmaxf(s2, s3)), s4);
  float e0 = __expf(s0 - mx), e1 = __expf(s1 - mx), e2 = __expf(s2 - mx);
  float e3 = __expf(s3 - mx), e4 = __expf(s4 - mx);
  float inv = __fdividef(1.0f, e0 + e1 + e2 + e3 + e4);
  float q0 = e0 * inv, q1 = e1 * inv, q2 = e2 * inv;
  float q3 = e3 * inv * m3, q4 = e4 * inv * m4;

  float4 atA, atB, gsA, gsB;
  WSUM4(atA, owA); WSUM4(atB, owB);
  WSUM4(gsA, gwA); WSUM4(gsB, gwB);

  stA = gate_out(pmA[SLOT], pgA[SLOT], atA, gsA);
  stB = gate_out(pmB[SLOT], pgB[SLOT], atB, gsB);

  reinterpret_cast<float4*>(&outl[SLOT][0])[lane] = stA;
  reinterpret_cast<float4*>(&outl[SLOT][256])[lane] = stB;

  if (FLUSH) {
#pragma unroll
    for (int s = 0; s < 8; s++) {
      float4 va = reinterpret_cast<float4*>(&outl[s][0])[lane];
      float4 vb = reinterpret_cast<float4*>(&outl[s][256])[lane];
      float* dst = po + (size_t)(t - 7 + s) * Dq + lane * 4;
      *reinterpret_cast<float4*>(dst) = va;
      *reinterpret_cast<float4*>(dst + 256) = vb;
    }
  }
}

__global__ __launch_bounds__(64, 1) void scan_kernel(
    const float* __restrict__ O, const float* __restrict__ Gm,
    const float* __restrict__ Pg, const float* __restrict__ Pm,
    float* __restrict__ out) {
  __shared__ float outl[8][Dq];
  int b = blockIdx.x;
  int lane = threadIdx.x;
  const float* ob  = O  + (size_t)b * Tq * Dq;
  const float* Gb  = Gm + (size_t)b * Tq * Dq;
  const float* Pgb = Pg + (size_t)b * Tq * Dq;
  const float* pmb = Pm + (size_t)b * Tq * Dq;
  float* po = out + (size_t)b * Tq * Dq;

  float4 owA[8], owB[8], gwA[8], gwB[8], pmA[8], pmB[8], pgA[8], pgB[8];
  float4 stA = make_float4(0.f, 0.f, 0.f, 0.f);
  float4 stB = make_float4(0.f, 0.f, 0.f, 0.f);

#pragma unroll
  for (int r = 0; r < 5; r++) {
    load_row(ob,  r, lane, owA[r], owB[r]);
    load_row(Gb,  r, lane, gwA[r], gwB[r]);
    load_row(pmb, r, lane, pmA[r], pmB[r]);
    load_row(Pgb, r, lane, pgA[r], pgB[r]);
  }

  scan_step<0,1,2,3,4, 0, 5, false>(0, 0.f, 0.f, ob, Gb, Pgb, pmb, po,
      owA,owB,gwA,gwB,pmA,pmB,pgA,pgB, stA,stB, lane, outl);
  scan_step<0,1,2,3,4, 1, 6, false>(1, 1.f, 0.f, ob, Gb, Pgb, pmb, po,
      owA,owB,gwA,gwB,pmA,pmB,pgA,pgB, stA,stB, lane, outl);

  for (int tb = 2; tb <= 2034; tb += 8) {
    scan_step<0,1,2,3,4, 2, 7, false>(tb+0, 1.f, 1.f, ob, Gb, Pgb, pmb, po,
        owA,owB,gwA,gwB,pmA,pmB,pgA,pgB, stA,stB, lane, outl);
    scan_step<1,2,3,4,5, 3, 0, false>(tb+1, 1.f, 1.f, ob, Gb, Pgb, pmb, po,
        owA,owB,gwA,gwB,pmA,pmB,pgA,pgB, stA,stB, lane, outl);
    scan_step<2,3,4,5,6, 4, 1, false>(tb+2, 1.f, 1.f, ob, Gb, Pgb, pmb, po,
        owA,owB,gwA,gwB,pmA,pmB,pgA,pgB, stA,stB, lane, outl);
    scan_step<3,4,5,6,7, 5, 2, false>(tb+3, 1.f, 1.f, ob, Gb, Pgb, pmb, po,
        owA,owB,gwA,gwB,pmA,pmB,pgA,pgB, stA,stB, lane, outl);
    scan_step<4,5,6,7,0, 6, 3, false>(tb+4, 1.f, 1.f, ob, Gb, Pgb, pmb, po,
        owA,owB,gwA,gwB,pmA,pmB,pgA,pgB, stA,stB, lane, outl);
    scan_step<5,6,7,0,1, 7, 4, true >(tb+5, 1.f, 1.f, ob, Gb, Pgb, pmb, po,
        owA,owB,gwA,gwB,pmA,pmB,pgA,pgB, stA,stB, lane, outl);
    scan_step<6,7,0,1,2, 0, 5, false>(tb+6, 1.f, 1.f, ob, Gb, Pgb, pmb, po,
        owA,owB,gwA,gwB,pmA,pmB,pgA,pgB, stA,stB, lane, outl);
    scan_step<7,0,1,2,3, 1, 6, false>(tb+7, 1.f, 1.f, ob, Gb, Pgb, pmb, po,
        owA,owB,gwA,gwB,pmA,pmB,pgA,pgB, stA,stB, lane, outl);
  }
  scan_step<0,1,2,3,4, 2, 7, false>(2042, 1.f, 1.f, ob, Gb, Pgb, pmb, po,
      owA,owB,gwA,gwB,pmA,pmB,pgA,pgB, stA,stB, lane, outl);
  scan_step<1,2,3,4,5, 3, 0, false>(2043, 1.f, 1.f, ob, Gb, Pgb, pmb, po,
      owA,owB,gwA,gwB,pmA,pmB,pgA,pgB, stA,stB, lane, outl);
  scan_step<2,3,4,5,6, 4, 1, false>(2044, 1.f, 1.f, ob, Gb, Pgb, pmb, po,
      owA,owB,gwA,gwB,pmA,pmB,pgA,pgB, stA,stB, lane, outl);
  scan_step<3,4,5,6,7, 5, 2, false>(2045, 1.f, 1.f, ob, Gb, Pgb, pmb, po,
      owA,owB,gwA,gwB,pmA,pmB,pgA,pgB, stA,stB, lane, outl);
  scan_step<4,5,6,7,0, 6, 3, false>(2046, 1.f, 0.f, ob, Gb, Pgb, pmb, po,
      owA,owB,gwA,gwB,pmA,pmB,pgA,pgB, stA,stB, lane, outl);
  scan_step<5,6,7,0,1, 7, 4, true >(2047, 0.f, 0.f, ob, Gb, Pgb, pmb, po,
      owA,owB,gwA,gwB,pmA,pmB,pgA,pgB, stA,stB, lane, outl);
}

// ---------------------------------------------------------------------------
// f32 fallback GEMM (only if ws too small) — R1 kernel, verified.
// ---------------------------------------------------------------------------
__global__ __launch_bounds__(256) void gemm_pre(
    const float* __restrict__ O, const float* __restrict__ Wm,
    const float* __restrict__ Wg, const float* __restrict__ bm,
    const float* __restrict__ bg, float* __restrict__ Pm,
    float* __restrict__ Pg, float* __restrict__ Gm, int mode) {
  const int BM = 128, BN = 128, BK = 16;
  __shared__ float As[BK][132];
  __shared__ float Bs[BK][132];
  int tidx = threadIdx.x;
  int bt0 = blockIdx.x * BM;
  int b = bt0 / Tq;
  int t0 = bt0 % Tq;
  int n0 = blockIdx.y * BN;
  int K = mode ? Dq : 5 * Dq;
  int tx = tidx % 16, ty = tidx / 16, lr = tidx >> 2, lc = (tidx & 3) * 4;
  float acc[8][8];
#pragma unroll
  for (int i = 0; i < 8; i++)
#pragma unroll
    for (int j = 0; j < 8; j++) acc[i][j] = 0.f;
  for (int kb = 0; kb < K; kb += BK) {
#pragma unroll
    for (int h = 0; h < 2; h++) {
      int m = lr + h * 64;
      int t = t0 + m;
      float4 av;
      if (mode == 0) {
        int j = kb >> 9;
        int kcol = (kb & 511) + lc;
        int sh = 2 - t; if (sh < 0) sh = 0;
        int r = t - 2 + j + sh;
        int hi = t + 2; if (hi > Tq - 1) hi = Tq - 1;
        int lo2 = t - 2; if (lo2 < 0) lo2 = 0;
        int nv = hi - lo2 + 1;
        if (j < nv) av = *reinterpret_cast<const float4*>(O + ((size_t)b * Tq + r) * Dq + kcol);
        else av = make_float4(0.f, 0.f, 0.f, 0.f);
      } else {
        av = *reinterpret_cast<const float4*>(O + ((size_t)b * Tq + t) * Dq + kb + lc);
      }
      As[lc + 0][m] = av.x; As[lc + 1][m] = av.y;
      As[lc + 2][m] = av.z; As[lc + 3][m] = av.w;
    }
#pragma unroll
    for (int h = 0; h < 2; h++) {
      int n = lr + h * 64;
      int gn = n0 + n;
      const float* wrow;
      int col;
      if (mode == 0) {
        if (gn < 512) { wrow = Wm + (size_t)gn * 2560; col = kb + lc; }
        else          { wrow = Wg + (size_t)(gn - 512) * 3072; col = kb + lc; }
      } else {
        wrow = Wg + (size_t)gn * 3072; col = 2560 + kb + lc;
      }
      float4 bv = *reinterpret_cast<const float4*>(wrow + col);
      Bs[lc + 0][n] = bv.x; Bs[lc + 1][n] = bv.y;
      Bs[lc + 2][n] = bv.z; Bs[lc + 3][n] = bv.w;
    }
    __syncthreads();
#pragma unroll
    for (int kk = 0; kk < BK; kk++) {
      float a[8], bb[8];
      float4 a0 = *reinterpret_cast<float4*>(&As[kk][ty * 8]);
      float4 a1 = *reinterpret_cast<float4*>(&As[kk][ty * 8 + 4]);
      float4 b0 = *reinterpret_cast<float4*>(&Bs[kk][tx * 8]);
      float4 b1 = *reinterpret_cast<float4*>(&Bs[kk][tx * 8 + 4]);
      a[0]=a0.x; a[1]=a0.y; a[2]=a0.z; a[3]=a0.w; a[4]=a1.x; a[5]=a1.y; a[6]=a1.z; a[7]=a1.w;
      bb[0]=b0.x; bb[1]=b0.y; bb[2]=b0.z; bb[3]=b0.w; bb[4]=b1.x; bb[5]=b1.y; bb[6]=b1.z; bb[7]=b1.w;
#pragma unroll
      for (int i = 0; i < 8; i++)
#pragma unroll
        for (int j = 0; j < 8; j++) acc[i][j] = fmaf(a[i], bb[j], acc[i][j]);
    }
    __syncthreads();
  }
  int gn = n0 + tx * 8;
  float bias[8];
  float* dstbase;
  int coloff;
  if (mode == 0) {
    if (gn < 512) {
#pragma unroll
      for (int j = 0; j < 8; j++) bias[j] = bm[gn + j];
      dstbase = Pm; coloff = gn;
    } else {
#pragma unroll
      for (int j = 0; j < 8; j++) bias[j] = bg[gn - 512 + j];
      dstbase = Pg; coloff = gn - 512;
    }
  } else {
#pragma unroll
    for (int j = 0; j < 8; j++) bias[j] = 0.f;
    dstbase = Gm; coloff = gn;
  }
#pragma unroll
  for (int i = 0; i < 8; i++) {
    int bt = bt0 + ty * 8 + i;
    float4 v0 = make_float4(acc[i][0] + bias[0], acc[i][1] + bias[1],
                            acc[i][2] + bias[2], acc[i][3] + bias[3]);
    float4 v1 = make_float4(acc[i][4] + bias[4], acc[i][5] + bias[5],
                            acc[i][6] + bias[6], acc[i][7] + bias[7]);
    float4* d = reinterpret_cast<float4*>(dstbase + (size_t)bt * Dq + coloff);
    d[0] = v0;
    d[1] = v1;
  }
}

extern "C" void kernel_launch(void* const* d_in, const int* in_sizes, int n_in,
                              void* d_out, int out_size, void* d_ws, size_t ws_size,
                              hipStream_t stream) {
  const float* O  = (const float*)d_in[0];
  const float* Wm = (const float*)d_in[1];
  const float* bm = (const float*)d_in[2];
  const float* Wg = (const float*)d_in[3];
  const float* bg = (const float*)d_in[4];
  float* out = (float*)d_out;

  const size_t NTOT = (size_t)Bq * Tq * Dq;   // 8.39M
  const size_t NWM = 512 * 2560, NWG = 512 * 3072;
  float* Pg = (float*)d_ws;
  float* Gm = Pg + NTOT;
  ushort* OHI = (ushort*)(Gm + NTOT);
  ushort* OLO = OHI + NTOT;
  ushort* WMH = OLO + NTOT;
  ushort* WML = WMH + NWM;
  ushort* WGH = WML + NWM;
  ushort* WGL = WGH + NWG;

  size_t need_split = 2 * NTOT * 4 + 2 * (NTOT + NWM + NWG) * 2;  // 112.2 MB
  if (ws_size >= need_split) {
    float* Pm = out;  // PRE_mlp staged in d_out (R2-proven in-place pattern)
    cvt_f16split<<<dim3((NTOT / 8 + 255) / 256), dim3(256), 0, stream>>>(O, OHI, OLO, NTOT / 8);
    cvt_f16split<<<dim3((NWM / 8 + 255) / 256), dim3(256), 0, stream>>>(Wm, WMH, WML, NWM / 8);
    cvt_f16split<<<dim3((NWG / 8 + 255) / 256), dim3(256), 0, stream>>>(Wg, WGH, WGL, NWG / 8);
    gemm_mfma<0><<<dim3(128, 8), dim3(256), 0, stream>>>(OHI, OLO, WMH, WML, WGH, WGL, bm, bg, Pm, Pg, Gm);
    gemm_mfma<1><<<dim3(128, 4), dim3(256), 0, stream>>>(OHI, OLO, WMH, WML, WGH, WGL, bm, bg, Pm, Pg, Gm);
    scan_kernel<<<dim3(Bq), dim3(64), 0, stream>>>(O, Gm, Pg, Pm, out);
  } else {
    bool sep = ws_size >= (size_t)3 * NTOT * sizeof(float);
    float* Pm = sep ? (Gm + NTOT) : out;
    gemm_pre<<<dim3(128, 8), dim3(256), 0, stream>>>(O, Wm, Wg, bm, bg, Pm, Pg, Gm, 0);
    gemm_pre<<<dim3(128, 4), dim3(256), 0, stream>>>(O, Wm, Wg, bm, bg, Pm, Pg, Gm, 1);
    scan_kernel<<<dim3(Bq), dim3(64), 0, stream>>>(O, Gm, Pg, Pm, out);
  }
}

// Round 13
// 1779.315 us; speedup vs baseline: 1.9491x; 1.2516x over previous
//
#include <hip/hip_runtime.h>

#define Bq 8
#define Tq 2048
#define Dq 512

typedef __attribute__((ext_vector_type(8))) _Float16 f16x8;  // 8 f16 = 4 VGPRs
typedef __attribute__((ext_vector_type(8))) short u16x8;
typedef __attribute__((ext_vector_type(4))) float f32x4;

// ---------------------------------------------------------------------------
// f32 -> (hi,lo) f16 split planes, x*256 pre-scale (undone by 2^-16 in GEMM).
// ---------------------------------------------------------------------------
__global__ __launch_bounds__(256) void cvt_f16split(
    const float* __restrict__ s, ushort* __restrict__ hi,
    ushort* __restrict__ lo, int n8) {
  int i = blockIdx.x * 256 + threadIdx.x;
  if (i >= n8) return;
  const float4* sp = reinterpret_cast<const float4*>(s) + i * 2;
  float4 a = sp[0], b = sp[1];
  float x[8] = {a.x, a.y, a.z, a.w, b.x, b.y, b.z, b.w};
  ushort h[8], l[8];
#pragma unroll
  for (int e = 0; e < 8; e++) {
    float xs = x[e] * 256.0f;
    _Float16 hh = (_Float16)xs;
    _Float16 ll = (_Float16)(xs - (float)hh);
    h[e] = *(ushort*)&hh;
    l[e] = *(ushort*)&ll;
  }
  *reinterpret_cast<u16x8*>(hi + (size_t)i * 8) = *reinterpret_cast<u16x8*>(h);
  *reinterpret_cast<u16x8*>(lo + (size_t)i * 8) = *reinterpret_cast<u16x8*>(l);
}

// ===========================================================================
// Scan helpers (R12-verified).
// ===========================================================================
template <int CTRL>
__device__ __forceinline__ float dppadd(float v) {
  int r = __builtin_amdgcn_update_dpp(0, __float_as_int(v), CTRL, 0xF, 0xF, true);
  return v + __int_as_float(r);
}
__device__ __forceinline__ float wave_sum_bcast(float v) {
  v = dppadd<0x111>(v);
  v = dppadd<0x112>(v);
  v = dppadd<0x114>(v);
  v = dppadd<0x118>(v);
  v = dppadd<0x142>(v);
  v = dppadd<0x143>(v);
  return __int_as_float(__builtin_amdgcn_readlane(__float_as_int(v), 63));
}

__device__ __forceinline__ void load_row(const float* __restrict__ base, int r,
                                         int lane, float4& a, float4& b) {
  const float* p = base + (size_t)r * Dq + lane * 4;
  a = *reinterpret_cast<const float4*>(p);
  b = *reinterpret_cast<const float4*>(p + 256);
}

__device__ __forceinline__ float dot8(const float4& xa, const float4& xb,
                                      const float4& ya, const float4& yb) {
  float s = xa.x * ya.x;
  s = fmaf(xa.y, ya.y, s); s = fmaf(xa.z, ya.z, s); s = fmaf(xa.w, ya.w, s);
  s = fmaf(xb.x, yb.x, s); s = fmaf(xb.y, yb.y, s);
  s = fmaf(xb.z, yb.z, s); s = fmaf(xb.w, yb.w, s);
  return s;
}

__device__ __forceinline__ float4 gate_out(const float4& pm, const float4& pg,
                                           const float4& at, const float4& gs) {
  float4 o;
  o.x = fmaf(at.x, __fdividef(1.f, 1.f + __expf(-(pg.x + gs.x))), pm.x);
  o.y = fmaf(at.y, __fdividef(1.f, 1.f + __expf(-(pg.y + gs.y))), pm.y);
  o.z = fmaf(at.z, __fdividef(1.f, 1.f + __expf(-(pg.z + gs.z))), pm.z);
  o.w = fmaf(at.w, __fdividef(1.f, 1.f + __expf(-(pg.w + gs.w))), pm.w);
  return o;
}

#define WSUM4(dst, arr)                                                        \
  dst.x = q0 * arr[S0].x + q1 * arr[S1].x + q2 * arr[S2].x + q3 * arr[S3].x +  \
          q4 * arr[S4].x;                                                      \
  dst.y = q0 * arr[S0].y + q1 * arr[S1].y + q2 * arr[S2].y + q3 * arr[S3].y +  \
          q4 * arr[S4].y;                                                      \
  dst.z = q0 * arr[S0].z + q1 * arr[S1].z + q2 * arr[S2].z + q3 * arr[S3].z +  \
          q4 * arr[S4].z;                                                      \
  dst.w = q0 * arr[S0].w + q1 * arr[S1].w + q2 * arr[S2].w + q3 * arr[S3].w +  \
          q4 * arr[S4].w;

// Bounded agent-scope wait: done[idx] >= target (monotone counter; bound
// turns a protocol bug into an absmax failure instead of a 600s timeout).
__device__ __forceinline__ void wait_band(int* done, int idx, int target) {
  int it = 0;
  while (__hip_atomic_load(&done[idx], __ATOMIC_ACQUIRE,
                           __HIP_MEMORY_SCOPE_AGENT) < target) {
    __builtin_amdgcn_s_sleep(8);
    if (++it > (1 << 22)) break;
  }
}

// One scan step (R12-verified) + band gate on the row-(t+5) prefetch.
template <int S0, int S1, int S2, int S3, int S4, int SLOT, int SLW, bool FLUSH>
__device__ __forceinline__ void scan_step(
    int t, float m3, float m4,
    const float* __restrict__ ob, const float* __restrict__ Gb,
    const float* __restrict__ Pgb, const float* __restrict__ pmb,
    float* __restrict__ po,
    float4 (&owA)[8], float4 (&owB)[8], float4 (&gwA)[8], float4 (&gwB)[8],
    float4 (&pmA)[8], float4 (&pmB)[8], float4 (&pgA)[8], float4 (&pgB)[8],
    float4& stA, float4& stB, int lane, float (*outl)[Dq],
    int* done, int bb, int& bandReady) {
  int rw = t + 5; if (rw > Tq - 1) rw = Tq - 1;
  int band = rw >> 7;
  if (band > bandReady) {          // once per 128 steps: gate on producers
    wait_band(done, bb + band, 12);
    bandReady = band;
  }
  __builtin_amdgcn_sched_barrier(0);
  load_row(ob,  rw, lane, owA[SLW], owB[SLW]);
  load_row(Gb,  rw, lane, gwA[SLW], gwB[SLW]);
  load_row(pmb, rw, lane, pmA[SLW], pmB[SLW]);
  load_row(Pgb, rw, lane, pgA[SLW], pgB[SLW]);
  __builtin_amdgcn_sched_barrier(0);

  float s0 = dot8(stA, stB, owA[S0], owB[S0]);
  float s1 = dot8(stA, stB, owA[S1], owB[S1]);
  float s2 = dot8(stA, stB, owA[S2], owB[S2]);
  float s3 = dot8(stA, stB, owA[S3], owB[S3]);
  float s4 = dot8(stA, stB, owA[S4], owB[S4]);
  const float scale = 0.04419417382415922f;
  s0 = wave_sum_bcast(s0) * scale;
  s1 = wave_sum_bcast(s1) * scale;
  s2 = wave_sum_bcast(s2) * scale;
  s3 = wave_sum_bcast(s3) * (scale * m3);
  s4 = wave_sum_bcast(s4) * (scale * m4);

  float mx = fmaxf(fmaxf(fmaxf(s0, s1), fmaxf(s2, s3)), s4);
  float e0 = __expf(s0 - mx), e1 = __expf(s1 - mx), e2 = __expf(s2 - mx);
  float e3 = __expf(s3 - mx), e4 = __expf(s4 - mx);
  float inv = __fdividef(1.0f, e0 + e1 + e2 + e3 + e4);
  float q0 = e0 * inv, q1 = e1 * inv, q2 = e2 * inv;
  float q3 = e3 * inv * m3, q4 = e4 * inv * m4;

  float4 atA, atB, gsA, gsB;
  WSUM4(atA, owA); WSUM4(atB, owB);
  WSUM4(gsA, gwA); WSUM4(gsB, gwB);

  stA = gate_out(pmA[SLOT], pgA[SLOT], atA, gsA);
  stB = gate_out(pmB[SLOT], pgB[SLOT], atB, gsB);

  reinterpret_cast<float4*>(&outl[SLOT][0])[lane] = stA;
  reinterpret_cast<float4*>(&outl[SLOT][256])[lane] = stB;

  if (FLUSH) {
#pragma unroll
    for (int s = 0; s < 8; s++) {
      float4 va = reinterpret_cast<float4*>(&outl[s][0])[lane];
      float4 vb = reinterpret_cast<float4*>(&outl[s][256])[lane];
      float* dst = po + (size_t)(t - 7 + s) * Dq + lane * 4;
      *reinterpret_cast<float4*>(dst) = va;
      *reinterpret_cast<float4*>(dst + 256) = vb;
    }
  }
}

// ===========================================================================
// FUSED kernel: blocks 0..7 = per-batch scans; blocks 8.. = GEMM producers in
// band-major order. Producers publish done[b*16+band] (12 tiles per band:
// 8 mode0-by + 4 mode1-by) with release semantics; scans gate prefetches.
// ===========================================================================
__global__ __launch_bounds__(256, 1) void fused_kernel(
    const float* __restrict__ O,
    const ushort* __restrict__ Ohi, const ushort* __restrict__ Olo,
    const ushort* __restrict__ Wmh, const ushort* __restrict__ Wml,
    const ushort* __restrict__ Wgh, const ushort* __restrict__ Wgl,
    const float* __restrict__ bm, const float* __restrict__ bg,
    float* __restrict__ Pg, float* __restrict__ Gm,
    float* __restrict__ out, int* __restrict__ done) {
  __shared__ float outl[8][Dq];  // scan staging (GEMM blocks don't touch)

  if (blockIdx.x < 8) {
    // ---------------- scan (one wave per batch) ----------------
    if (threadIdx.x >= 64) return;
    int b = blockIdx.x;
    int lane = threadIdx.x;
    int bb = b * 16;
    const float* ob  = O   + (size_t)b * Tq * Dq;
    const float* Gb  = Gm  + (size_t)b * Tq * Dq;
    const float* Pgb = Pg  + (size_t)b * Tq * Dq;
    const float* pmb = out + (size_t)b * Tq * Dq;  // PRE_mlp lives in d_out
    float* po = out + (size_t)b * Tq * Dq;

    int bandReady = -1;
    wait_band(done, bb + 0, 12);   // prologue reads rows 0..4
    bandReady = 0;
    __builtin_amdgcn_sched_barrier(0);

    float4 owA[8], owB[8], gwA[8], gwB[8], pmA[8], pmB[8], pgA[8], pgB[8];
    float4 stA = make_float4(0.f, 0.f, 0.f, 0.f);
    float4 stB = make_float4(0.f, 0.f, 0.f, 0.f);
#pragma unroll
    for (int r = 0; r < 5; r++) {
      load_row(ob,  r, lane, owA[r], owB[r]);
      load_row(Gb,  r, lane, gwA[r], gwB[r]);
      load_row(pmb, r, lane, pmA[r], pmB[r]);
      load_row(Pgb, r, lane, pgA[r], pgB[r]);
    }

    scan_step<0,1,2,3,4, 0, 5, false>(0, 0.f, 0.f, ob, Gb, Pgb, pmb, po,
        owA,owB,gwA,gwB,pmA,pmB,pgA,pgB, stA,stB, lane, outl, done, bb, bandReady);
    scan_step<0,1,2,3,4, 1, 6, false>(1, 1.f, 0.f, ob, Gb, Pgb, pmb, po,
        owA,owB,gwA,gwB,pmA,pmB,pgA,pgB, stA,stB, lane, outl, done, bb, bandReady);
    for (int tb = 2; tb <= 2034; tb += 8) {
      scan_step<0,1,2,3,4, 2, 7, false>(tb+0, 1.f, 1.f, ob, Gb, Pgb, pmb, po,
          owA,owB,gwA,gwB,pmA,pmB,pgA,pgB, stA,stB, lane, outl, done, bb, bandReady);
      scan_step<1,2,3,4,5, 3, 0, false>(tb+1, 1.f, 1.f, ob, Gb, Pgb, pmb, po,
          owA,owB,gwA,gwB,pmA,pmB,pgA,pgB, stA,stB, lane, outl, done, bb, bandReady);
      scan_step<2,3,4,5,6, 4, 1, false>(tb+2, 1.f, 1.f, ob, Gb, Pgb, pmb, po,
          owA,owB,gwA,gwB,pmA,pmB,pgA,pgB, stA,stB, lane, outl, done, bb, bandReady);
      scan_step<3,4,5,6,7, 5, 2, false>(tb+3, 1.f, 1.f, ob, Gb, Pgb, pmb, po,
          owA,owB,gwA,gwB,pmA,pmB,pgA,pgB, stA,stB, lane, outl, done, bb, bandReady);
      scan_step<4,5,6,7,0, 6, 3, false>(tb+4, 1.f, 1.f, ob, Gb, Pgb, pmb, po,
          owA,owB,gwA,gwB,pmA,pmB,pgA,pgB, stA,stB, lane, outl, done, bb, bandReady);
      scan_step<5,6,7,0,1, 7, 4, true >(tb+5, 1.f, 1.f, ob, Gb, Pgb, pmb, po,
          owA,owB,gwA,gwB,pmA,pmB,pgA,pgB, stA,stB, lane, outl, done, bb, bandReady);
      scan_step<6,7,0,1,2, 0, 5, false>(tb+6, 1.f, 1.f, ob, Gb, Pgb, pmb, po,
          owA,owB,gwA,gwB,pmA,pmB,pgA,pgB, stA,stB, lane, outl, done, bb, bandReady);
      scan_step<7,0,1,2,3, 1, 6, false>(tb+7, 1.f, 1.f, ob, Gb, Pgb, pmb, po,
          owA,owB,gwA,gwB,pmA,pmB,pgA,pgB, stA,stB, lane, outl, done, bb, bandReady);
    }
    scan_step<0,1,2,3,4, 2, 7, false>(2042, 1.f, 1.f, ob, Gb, Pgb, pmb, po,
        owA,owB,gwA,gwB,pmA,pmB,pgA,pgB, stA,stB, lane, outl, done, bb, bandReady);
    scan_step<1,2,3,4,5, 3, 0, false>(2043, 1.f, 1.f, ob, Gb, Pgb, pmb, po,
        owA,owB,gwA,gwB,pmA,pmB,pgA,pgB, stA,stB, lane, outl, done, bb, bandReady);
    scan_step<2,3,4,5,6, 4, 1, false>(2044, 1.f, 1.f, ob, Gb, Pgb, pmb, po,
        owA,owB,gwA,gwB,pmA,pmB,pgA,pgB, stA,stB, lane, outl, done, bb, bandReady);
    scan_step<3,4,5,6,7, 5, 2, false>(2045, 1.f, 1.f, ob, Gb, Pgb, pmb, po,
        owA,owB,gwA,gwB,pmA,pmB,pgA,pgB, stA,stB, lane, outl, done, bb, bandReady);
    scan_step<4,5,6,7,0, 6, 3, false>(2046, 1.f, 0.f, ob, Gb, Pgb, pmb, po,
        owA,owB,gwA,gwB,pmA,pmB,pgA,pgB, stA,stB, lane, outl, done, bb, bandReady);
    scan_step<5,6,7,0,1, 7, 4, true >(2047, 0.f, 0.f, ob, Gb, Pgb, pmb, po,
        owA,owB,gwA,gwB,pmA,pmB,pgA,pgB, stA,stB, lane, outl, done, bb, bandReady);
    return;
  }

  // ---------------- GEMM producer (R12-verified split-f16 direct-gather) ----
  int g = blockIdx.x - 8;
  int band = g / 96;
  int rem = g % 96;
  int bat = rem / 12;
  int role = rem % 12;            // 0..7: mode0 by=role; 8..11: mode1 by=role-8
  int bt0 = (bat * 16 + band) * 128;
  int gb = bat * Tq;
  int t0 = bt0 % Tq;

  int tid = threadIdx.x;
  int l = tid & 63, w = tid >> 6;
  int wm = w >> 1, wn = w & 1;
  int r16 = l & 15, kg = l >> 4;

  f32x4 acc[4][4] = {};
  const f16x8 zz = {0, 0, 0, 0, 0, 0, 0, 0};

  if (role >= 8) {
    // ---- MODE 1: G = O @ Wg[:, 2560:]^T ----
    int by = role - 8;
    const ushort *bph[4], *bpl[4];
    int ncol[4];
#pragma unroll
    for (int ni = 0; ni < 4; ni++) {
      int n_g = by * 128 + wn * 64 + ni * 16 + r16;
      ncol[ni] = n_g;
      size_t off = (size_t)n_g * 3072 + 2560 + kg * 8;
      bph[ni] = Wgh + off; bpl[ni] = Wgl + off;
    }
    const ushort *aph[4], *apl[4];
#pragma unroll
    for (int mi = 0; mi < 4; mi++) {
      size_t off = (size_t)(bt0 + wm * 64 + mi * 16 + r16) * Dq + kg * 8;
      aph[mi] = Ohi + off; apl[mi] = Olo + off;
    }
#pragma unroll 4
    for (int ks = 0; ks < 16; ks++) {
      f16x8 Ah[4], Al[4], Bh[4], Bl[4];
#pragma unroll
      for (int mi = 0; mi < 4; mi++) {
        Ah[mi] = *(const f16x8*)aph[mi]; aph[mi] += 32;
        Al[mi] = *(const f16x8*)apl[mi]; apl[mi] += 32;
      }
#pragma unroll
      for (int ni = 0; ni < 4; ni++) {
        Bh[ni] = *(const f16x8*)bph[ni]; bph[ni] += 32;
        Bl[ni] = *(const f16x8*)bpl[ni]; bpl[ni] += 32;
      }
#pragma unroll
      for (int mi = 0; mi < 4; mi++)
#pragma unroll
        for (int ni = 0; ni < 4; ni++) {
          acc[mi][ni] = __builtin_amdgcn_mfma_f32_16x16x32_f16(Ah[mi], Bh[ni], acc[mi][ni], 0, 0, 0);
          acc[mi][ni] = __builtin_amdgcn_mfma_f32_16x16x32_f16(Al[mi], Bh[ni], acc[mi][ni], 0, 0, 0);
          acc[mi][ni] = __builtin_amdgcn_mfma_f32_16x16x32_f16(Ah[mi], Bl[ni], acc[mi][ni], 0, 0, 0);
        }
    }
    const float SC = 1.0f / 65536.0f;
#pragma unroll
    for (int ni = 0; ni < 4; ni++) {
#pragma unroll
      for (int mi = 0; mi < 4; mi++) {
        int rowb = bt0 + wm * 64 + mi * 16 + kg * 4;
#pragma unroll
        for (int rr = 0; rr < 4; rr++)
          Gm[(size_t)(rowb + rr) * Dq + ncol[ni]] = acc[mi][ni][rr] * SC;
      }
    }
  } else {
    // ---- MODE 0: PRE = windowflat @ {Wm | Wg[:, :2560]}^T + bias ----
    int by = role;
    const ushort *bph[4], *bpl[4];
    int ncol[4];
#pragma unroll
    for (int ni = 0; ni < 4; ni++) {
      int n_g = by * 128 + wn * 64 + ni * 16 + r16;
      ncol[ni] = n_g;
      size_t off;
      if (by < 4) { off = (size_t)n_g * 2560 + kg * 8; bph[ni] = Wmh + off; bpl[ni] = Wml + off; }
      else { off = (size_t)(n_g - 512) * 3072 + kg * 8; bph[ni] = Wgh + off; bpl[ni] = Wgl + off; }
    }
    int arow[4][5];
    uint vmask[4];
#pragma unroll
    for (int mi = 0; mi < 4; mi++) {
      int t = t0 + wm * 64 + mi * 16 + r16;
      int sh = 2 - t; if (sh < 0) sh = 0;
      int hi2 = t + 2; if (hi2 > Tq - 1) hi2 = Tq - 1;
      int lo2 = t - 2; if (lo2 < 0) lo2 = 0;
      int nv = hi2 - lo2 + 1;
      uint vm = 0;
#pragma unroll
      for (int j = 0; j < 5; j++) {
        int r = t - 2 + j + sh;
        if (r > Tq - 1) r = Tq - 1;
        arow[mi][j] = gb + r;
        if (j < nv) vm |= (1u << j);
      }
      vmask[mi] = vm;
    }
#pragma unroll
    for (int j = 0; j < 5; j++) {
      const ushort *aph[4], *apl[4];
      bool v[4];
#pragma unroll
      for (int mi = 0; mi < 4; mi++) {
        size_t off = (size_t)arow[mi][j] * Dq + kg * 8;
        aph[mi] = Ohi + off; apl[mi] = Olo + off;
        v[mi] = (vmask[mi] >> j) & 1u;
      }
#pragma unroll 4
      for (int ks = 0; ks < 16; ks++) {
        f16x8 Ah[4], Al[4], Bh[4], Bl[4];
#pragma unroll
        for (int mi = 0; mi < 4; mi++) {
          f16x8 th = *(const f16x8*)aph[mi]; aph[mi] += 32;
          f16x8 tl = *(const f16x8*)apl[mi]; apl[mi] += 32;
          Ah[mi] = v[mi] ? th : zz;
          Al[mi] = v[mi] ? tl : zz;
        }
#pragma unroll
        for (int ni = 0; ni < 4; ni++) {
          Bh[ni] = *(const f16x8*)bph[ni]; bph[ni] += 32;
          Bl[ni] = *(const f16x8*)bpl[ni]; bpl[ni] += 32;
        }
#pragma unroll
        for (int mi = 0; mi < 4; mi++)
#pragma unroll
          for (int ni = 0; ni < 4; ni++) {
            acc[mi][ni] = __builtin_amdgcn_mfma_f32_16x16x32_f16(Ah[mi], Bh[ni], acc[mi][ni], 0, 0, 0);
            acc[mi][ni] = __builtin_amdgcn_mfma_f32_16x16x32_f16(Al[mi], Bh[ni], acc[mi][ni], 0, 0, 0);
            acc[mi][ni] = __builtin_amdgcn_mfma_f32_16x16x32_f16(Ah[mi], Bl[ni], acc[mi][ni], 0, 0, 0);
          }
      }
    }
    const float SC = 1.0f / 65536.0f;
    float* dst = (by < 4) ? out : Pg;  // PRE_mlp -> d_out, PRE_gate -> ws
    const float* bias = (by < 4) ? bm : bg;
#pragma unroll
    for (int ni = 0; ni < 4; ni++) {
      int oc = (by < 4) ? ncol[ni] : ncol[ni] - 512;
      float bi = bias[oc];
#pragma unroll
      for (int mi = 0; mi < 4; mi++) {
        int rowb = bt0 + wm * 64 + mi * 16 + kg * 4;
#pragma unroll
        for (int rr = 0; rr < 4; rr++)
          dst[(size_t)(rowb + rr) * Dq + oc] = fmaf(acc[mi][ni][rr], SC, bi);
      }
    }
  }

  // ---- publish: all stores visible, then bump the band counter ----
  __threadfence();
  __syncthreads();
  if (tid == 0) {
    __hip_atomic_fetch_add(&done[bat * 16 + band], 1, __ATOMIC_RELEASE,
                           __HIP_MEMORY_SCOPE_AGENT);
  }
}

// ---------------------------------------------------------------------------
// f32 fallback (ws too small) — R1-verified serial path.
// ---------------------------------------------------------------------------
__global__ __launch_bounds__(256) void gemm_pre(
    const float* __restrict__ O, const float* __restrict__ Wm,
    const float* __restrict__ Wg, const float* __restrict__ bm,
    const float* __restrict__ bg, float* __restrict__ Pm,
    float* __restrict__ Pg, float* __restrict__ Gm, int mode) {
  const int BM = 128, BN = 128, BK = 16;
  __shared__ float As[BK][132];
  __shared__ float Bs[BK][132];
  int tidx = threadIdx.x;
  int bt0 = blockIdx.x * BM;
  int b = bt0 / Tq;
  int t0 = bt0 % Tq;
  int n0 = blockIdx.y * BN;
  int K = mode ? Dq : 5 * Dq;
  int tx = tidx % 16, ty = tidx / 16, lr = tidx >> 2, lc = (tidx & 3) * 4;
  float acc[8][8];
#pragma unroll
  for (int i = 0; i < 8; i++)
#pragma unroll
    for (int j = 0; j < 8; j++) acc[i][j] = 0.f;
  for (int kb = 0; kb < K; kb += BK) {
#pragma unroll
    for (int h = 0; h < 2; h++) {
      int m = lr + h * 64;
      int t = t0 + m;
      float4 av;
      if (mode == 0) {
        int j = kb >> 9;
        int kcol = (kb & 511) + lc;
        int sh = 2 - t; if (sh < 0) sh = 0;
        int r = t - 2 + j + sh;
        int hi = t + 2; if (hi > Tq - 1) hi = Tq - 1;
        int lo2 = t - 2; if (lo2 < 0) lo2 = 0;
        int nv = hi - lo2 + 1;
        if (j < nv) av = *reinterpret_cast<const float4*>(O + ((size_t)b * Tq + r) * Dq + kcol);
        else av = make_float4(0.f, 0.f, 0.f, 0.f);
      } else {
        av = *reinterpret_cast<const float4*>(O + ((size_t)b * Tq + t) * Dq + kb + lc);
      }
      As[lc + 0][m] = av.x; As[lc + 1][m] = av.y;
      As[lc + 2][m] = av.z; As[lc + 3][m] = av.w;
    }
#pragma unroll
    for (int h = 0; h < 2; h++) {
      int n = lr + h * 64;
      int gn = n0 + n;
      const float* wrow;
      int col;
      if (mode == 0) {
        if (gn < 512) { wrow = Wm + (size_t)gn * 2560; col = kb + lc; }
        else          { wrow = Wg + (size_t)(gn - 512) * 3072; col = kb + lc; }
      } else {
        wrow = Wg + (size_t)gn * 3072; col = 2560 + kb + lc;
      }
      float4 bv = *reinterpret_cast<const float4*>(wrow + col);
      Bs[lc + 0][n] = bv.x; Bs[lc + 1][n] = bv.y;
      Bs[lc + 2][n] = bv.z; Bs[lc + 3][n] = bv.w;
    }
    __syncthreads();
#pragma unroll
    for (int kk = 0; kk < BK; kk++) {
      float a[8], bb[8];
      float4 a0 = *reinterpret_cast<float4*>(&As[kk][ty * 8]);
      float4 a1 = *reinterpret_cast<float4*>(&As[kk][ty * 8 + 4]);
      float4 b0 = *reinterpret_cast<float4*>(&Bs[kk][tx * 8]);
      float4 b1 = *reinterpret_cast<float4*>(&Bs[kk][tx * 8 + 4]);
      a[0]=a0.x; a[1]=a0.y; a[2]=a0.z; a[3]=a0.w; a[4]=a1.x; a[5]=a1.y; a[6]=a1.z; a[7]=a1.w;
      bb[0]=b0.x; bb[1]=b0.y; bb[2]=b0.z; bb[3]=b0.w; bb[4]=b1.x; bb[5]=b1.y; bb[6]=b1.z; bb[7]=b1.w;
#pragma unroll
      for (int i = 0; i < 8; i++)
#pragma unroll
        for (int j = 0; j < 8; j++) acc[i][j] = fmaf(a[i], bb[j], acc[i][j]);
    }
    __syncthreads();
  }
  int gn = n0 + tx * 8;
  float bias[8];
  float* dstbase;
  int coloff;
  if (mode == 0) {
    if (gn < 512) {
#pragma unroll
      for (int j = 0; j < 8; j++) bias[j] = bm[gn + j];
      dstbase = Pm; coloff = gn;
    } else {
#pragma unroll
      for (int j = 0; j < 8; j++) bias[j] = bg[gn - 512 + j];
      dstbase = Pg; coloff = gn - 512;
    }
  } else {
#pragma unroll
    for (int j = 0; j < 8; j++) bias[j] = 0.f;
    dstbase = Gm; coloff = gn;
  }
#pragma unroll
  for (int i = 0; i < 8; i++) {
    int bt = bt0 + ty * 8 + i;
    float4 v0 = make_float4(acc[i][0] + bias[0], acc[i][1] + bias[1],
                            acc[i][2] + bias[2], acc[i][3] + bias[3]);
    float4 v1 = make_float4(acc[i][4] + bias[4], acc[i][5] + bias[5],
                            acc[i][6] + bias[6], acc[i][7] + bias[7]);
    float4* d = reinterpret_cast<float4*>(dstbase + (size_t)bt * Dq + coloff);
    d[0] = v0;
    d[1] = v1;
  }
}

__global__ __launch_bounds__(64, 1) void scan_only(
    const float* __restrict__ O, const float* __restrict__ Gm,
    const float* __restrict__ Pg, const float* __restrict__ Pm,
    float* __restrict__ out, int* __restrict__ done) {
  // Fallback serial scan: done[] pre-filled to 12 so gates are no-ops.
  __shared__ float outl[8][Dq];
  int b = blockIdx.x;
  int lane = threadIdx.x;
  int bb = b * 16;
  const float* ob  = O  + (size_t)b * Tq * Dq;
  const float* Gb  = Gm + (size_t)b * Tq * Dq;
  const float* Pgb = Pg + (size_t)b * Tq * Dq;
  const float* pmb = Pm + (size_t)b * Tq * Dq;
  float* po = out + (size_t)b * Tq * Dq;
  int bandReady = 15;

  float4 owA[8], owB[8], gwA[8], gwB[8], pmA[8], pmB[8], pgA[8], pgB[8];
  float4 stA = make_float4(0.f, 0.f, 0.f, 0.f);
  float4 stB = make_float4(0.f, 0.f, 0.f, 0.f);
#pragma unroll
  for (int r = 0; r < 5; r++) {
    load_row(ob,  r, lane, owA[r], owB[r]);
    load_row(Gb,  r, lane, gwA[r], gwB[r]);
    load_row(pmb, r, lane, pmA[r], pmB[r]);
    load_row(Pgb, r, lane, pgA[r], pgB[r]);
  }
  scan_step<0,1,2,3,4, 0, 5, false>(0, 0.f, 0.f, ob, Gb, Pgb, pmb, po,
      owA,owB,gwA,gwB,pmA,pmB,pgA,pgB, stA,stB, lane, outl, done, bb, bandReady);
  scan_step<0,1,2,3,4, 1, 6, false>(1, 1.f, 0.f, ob, Gb, Pgb, pmb, po,
      owA,owB,gwA,gwB,pmA,pmB,pgA,pgB, stA,stB, lane, outl, done, bb, bandReady);
  for (int tb = 2; tb <= 2034; tb += 8) {
    scan_step<0,1,2,3,4, 2, 7, false>(tb+0, 1.f, 1.f, ob, Gb, Pgb, pmb, po,
        owA,owB,gwA,gwB,pmA,pmB,pgA,pgB, stA,stB, lane, outl, done, bb, bandReady);
    scan_step<1,2,3,4,5, 3, 0, false>(tb+1, 1.f, 1.f, ob, Gb, Pgb, pmb, po,
        owA,owB,gwA,gwB,pmA,pmB,pgA,pgB, stA,stB, lane, outl, done, bb, bandReady);
    scan_step<2,3,4,5,6, 4, 1, false>(tb+2, 1.f, 1.f, ob, Gb, Pgb, pmb, po,
        owA,owB,gwA,gwB,pmA,pmB,pgA,pgB, stA,stB, lane, outl, done, bb, bandReady);
    scan_step<3,4,5,6,7, 5, 2, false>(tb+3, 1.f, 1.f, ob, Gb, Pgb, pmb, po,
        owA,owB,gwA,gwB,pmA,pmB,pgA,pgB, stA,stB, lane, outl, done, bb, bandReady);
    scan_step<4,5,6,7,0, 6, 3, false>(tb+4, 1.f, 1.f, ob, Gb, Pgb, pmb, po,
        owA,owB,gwA,gwB,pmA,pmB,pgA,pgB, stA,stB, lane, outl, done, bb, bandReady);
    scan_step<5,6,7,0,1, 7, 4, true >(tb+5, 1.f, 1.f, ob, Gb, Pgb, pmb, po,
        owA,owB,gwA,gwB,pmA,pmB,pgA,pgB, stA,stB, lane, outl, done, bb, bandReady);
    scan_step<6,7,0,1,2, 0, 5, false>(tb+6, 1.f, 1.f, ob, Gb, Pgb, pmb, po,
        owA,owB,gwA,gwB,pmA,pmB,pgA,pgB, stA,stB, lane, outl, done, bb, bandReady);
    scan_step<7,0,1,2,3, 1, 6, false>(tb+7, 1.f, 1.f, ob, Gb, Pgb, pmb, po,
        owA,owB,gwA,gwB,pmA,pmB,pgA,pgB, stA,stB, lane, outl, done, bb, bandReady);
  }
  scan_step<0,1,2,3,4, 2, 7, false>(2042, 1.f, 1.f, ob, Gb, Pgb, pmb, po,
      owA,owB,gwA,gwB,pmA,pmB,pgA,pgB, stA,stB, lane, outl, done, bb, bandReady);
  scan_step<1,2,3,4,5, 3, 0, false>(2043, 1.f, 1.f, ob, Gb, Pgb, pmb, po,
      owA,owB,gwA,gwB,pmA,pmB,pgA,pgB, stA,stB, lane, outl, done, bb, bandReady);
  scan_step<2,3,4,5,6, 4, 1, false>(2044, 1.f, 1.f, ob, Gb, Pgb, pmb, po,
      owA,owB,gwA,gwB,pmA,pmB,pgA,pgB, stA,stB, lane, outl, done, bb, bandReady);
  scan_step<3,4,5,6,7, 5, 2, false>(2045, 1.f, 1.f, ob, Gb, Pgb, pmb, po,
      owA,owB,gwA,gwB,pmA,pmB,pgA,pgB, stA,stB, lane, outl, done, bb, bandReady);
  scan_step<4,5,6,7,0, 6, 3, false>(2046, 1.f, 0.f, ob, Gb, Pgb, pmb, po,
      owA,owB,gwA,gwB,pmA,pmB,pgA,pgB, stA,stB, lane, outl, done, bb, bandReady);
  scan_step<5,6,7,0,1, 7, 4, true >(2047, 0.f, 0.f, ob, Gb, Pgb, pmb, po,
      owA,owB,gwA,gwB,pmA,pmB,pgA,pgB, stA,stB, lane, outl, done, bb, bandReady);
}

extern "C" void kernel_launch(void* const* d_in, const int* in_sizes, int n_in,
                              void* d_out, int out_size, void* d_ws, size_t ws_size,
                              hipStream_t stream) {
  const float* O  = (const float*)d_in[0];
  const float* Wm = (const float*)d_in[1];
  const float* bm = (const float*)d_in[2];
  const float* Wg = (const float*)d_in[3];
  const float* bg = (const float*)d_in[4];
  float* out = (float*)d_out;

  const size_t NTOT = (size_t)Bq * Tq * Dq;   // 8.39M
  const size_t NWM = 512 * 2560, NWG = 512 * 3072;
  float* Pg = (float*)d_ws;
  float* Gm = Pg + NTOT;
  ushort* OHI = (ushort*)(Gm + NTOT);
  ushort* OLO = OHI + NTOT;
  ushort* WMH = OLO + NTOT;
  ushort* WML = WMH + NWM;
  ushort* WGH = WML + NWM;
  ushort* WGL = WGH + NWG;
  int* done = (int*)(WGL + NWG);              // 128 ints

  size_t need = 2 * NTOT * 4 + 2 * (NTOT + NWM + NWG) * 2 + 128 * 4;
  if (ws_size >= need) {
    hipMemsetAsync(done, 0, 128 * 4, stream);
    cvt_f16split<<<dim3((NTOT / 8 + 255) / 256), dim3(256), 0, stream>>>(O, OHI, OLO, NTOT / 8);
    cvt_f16split<<<dim3((NWM / 8 + 255) / 256), dim3(256), 0, stream>>>(Wm, WMH, WML, NWM / 8);
    cvt_f16split<<<dim3((NWG / 8 + 255) / 256), dim3(256), 0, stream>>>(Wg, WGH, WGL, NWG / 8);
    fused_kernel<<<dim3(8 + 16 * 96), dim3(256), 0, stream>>>(
        O, OHI, OLO, WMH, WML, WGH, WGL, bm, bg, Pg, Gm, out, done);
  } else {
    bool sep = ws_size >= (size_t)(3 * NTOT * 4 + 128 * 4);
    float* Pm = sep ? (Gm + NTOT) : out;
    int* done2 = sep ? (int*)(Pm + NTOT) : (int*)(Gm + NTOT);
    hipMemsetAsync(done2, 12, 128 * 4, stream);  // every byte 12 -> >= 12
    gemm_pre<<<dim3(128, 8), dim3(256), 0, stream>>>(O, Wm, Wg, bm, bg, Pm, Pg, Gm, 0);
    gemm_pre<<<dim3(128, 4), dim3(256), 0, stream>>>(O, Wm, Wg, bm, bg, Pm, Pg, Gm, 1);
    scan_only<<<dim3(Bq), dim3(64), 0, stream>>>(O, Gm, Pg, Pm, out, done2);
  }
}

// Round 15
// 1778.600 us; speedup vs baseline: 1.9498x; 1.0004x over previous
//
#include <hip/hip_runtime.h>

#define Bq 8
#define Tq 2048
#define Dq 512

typedef __attribute__((ext_vector_type(8))) _Float16 f16x8;  // 8 f16 = 4 VGPRs
typedef __attribute__((ext_vector_type(8))) short u16x8;
typedef __attribute__((ext_vector_type(4))) float f32x4;

// ---------------------------------------------------------------------------
// f32 -> (hi,lo) f16 split planes, x*256 pre-scale (undone by 2^-16 in GEMM).
// ---------------------------------------------------------------------------
__global__ __launch_bounds__(256) void cvt_f16split(
    const float* __restrict__ s, ushort* __restrict__ hi,
    ushort* __restrict__ lo, int n8) {
  int i = blockIdx.x * 256 + threadIdx.x;
  if (i >= n8) return;
  const float4* sp = reinterpret_cast<const float4*>(s) + i * 2;
  float4 a = sp[0], b = sp[1];
  float x[8] = {a.x, a.y, a.z, a.w, b.x, b.y, b.z, b.w};
  ushort h[8], l[8];
#pragma unroll
  for (int e = 0; e < 8; e++) {
    float xs = x[e] * 256.0f;
    _Float16 hh = (_Float16)xs;
    _Float16 ll = (_Float16)(xs - (float)hh);
    h[e] = *(ushort*)&hh;
    l[e] = *(ushort*)&ll;
  }
  *reinterpret_cast<u16x8*>(hi + (size_t)i * 8) = *reinterpret_cast<u16x8*>(h);
  *reinterpret_cast<u16x8*>(lo + (size_t)i * 8) = *reinterpret_cast<u16x8*>(l);
}

// ===========================================================================
// Common helpers.
// ===========================================================================
template <int CTRL>
__device__ __forceinline__ float dppadd(float v) {
  int r = __builtin_amdgcn_update_dpp(0, __float_as_int(v), CTRL, 0xF, 0xF, true);
  return v + __int_as_float(r);
}
__device__ __forceinline__ float wave_sum_bcast(float v) {
  v = dppadd<0x111>(v);
  v = dppadd<0x112>(v);
  v = dppadd<0x114>(v);
  v = dppadd<0x118>(v);
  v = dppadd<0x142>(v);
  v = dppadd<0x143>(v);
  return __int_as_float(__builtin_amdgcn_readlane(__float_as_int(v), 63));
}

// Bounded agent-scope wait on a monotone counter (bug -> absmax fail, not hang).
__device__ __forceinline__ void wait_band(int* done, int idx, int target) {
  int it = 0;
  while (__hip_atomic_load(&done[idx], __ATOMIC_ACQUIRE,
                           __HIP_MEMORY_SCOPE_AGENT) < target) {
    __builtin_amdgcn_s_sleep(8);
    if (++it > (1 << 22)) break;
  }
}

// ===========================================================================
// 4-wave cooperative scan step. Wave w owns dims [128w,128w+128) (float2 per
// lane). Register rings (8 slots) per stream; prefetch row t+5 at step top
// (16 cache lines/step/wave = 1/4 of the 1-wave MLP saturation).
// NUMERICS ARE TRANSPLANTED VERBATIM FROM R5's PASSING KERNEL (absmax 0.0156
// with this exact 4-wave decomposition): mul-then-fma partials, per-wave
// scale+mask applied BEFORE publishing partials, fma-chain weighted sums,
// R5's exact gate expression. R14's ulp-level deviations (scale-after-sum)
// diverged chaotically from the reference (0.195) — do not re-derive.
// Cross-wave exchange: 5 lanes publish to red[t&1][j][w]; lgkmcnt(0) + raw
// s_barrier (vmcnt untouched so in-flight prefetches survive); each wave
// sums 4 partials and computes softmax redundantly. Double-buffered red[]
// is race-free by the barrier-per-step argument (reads of red[t&1] at step t
// complete before this wave reaches barrier t+1; writes to red[t&1] at step
// t+2 happen only after barrier t+1).
// ===========================================================================
template <int S0, int S1, int S2, int S3, int S4, int SLOT, int SLW>
__device__ __forceinline__ void scan_step4(
    int t, float m3, float m4, int lane, int w, int dbase,
    const float* __restrict__ ob, const float* __restrict__ Gb,
    const float* __restrict__ Pgb, const float* __restrict__ pmb,
    float* __restrict__ po, float (*red)[5][4],
    int* done, int bb, int& bandReady,
    float2 (&ow)[8], float2 (&gw)[8], float2 (&pm)[8], float2 (&pg)[8],
    float2& st) {
  int rw = t + 5; if (rw > Tq - 1) rw = Tq - 1;
  int band = rw >> 7;
  if (band > bandReady) {  // once per 128 steps: gate on producer progress
    wait_band(done, bb + band, 12);
    bandReady = band;
  }
  __builtin_amdgcn_sched_barrier(0);
  ow[SLW] = *(const float2*)(ob  + (size_t)rw * Dq + dbase);
  gw[SLW] = *(const float2*)(Gb  + (size_t)rw * Dq + dbase);
  pm[SLW] = *(const float2*)(pmb + (size_t)rw * Dq + dbase);
  pg[SLW] = *(const float2*)(Pgb + (size_t)rw * Dq + dbase);
  __builtin_amdgcn_sched_barrier(0);

  // ---- partial scores over this wave's 128 dims (R5-exact) ----
  const float scale = 0.04419417382415922f;  // 1/sqrt(512)
  float s0 = st.x * ow[S0].x; s0 = fmaf(st.y, ow[S0].y, s0);
  float s1 = st.x * ow[S1].x; s1 = fmaf(st.y, ow[S1].y, s1);
  float s2 = st.x * ow[S2].x; s2 = fmaf(st.y, ow[S2].y, s2);
  float s3 = st.x * ow[S3].x; s3 = fmaf(st.y, ow[S3].y, s3);
  float s4 = st.x * ow[S4].x; s4 = fmaf(st.y, ow[S4].y, s4);
  s0 = wave_sum_bcast(s0);
  s1 = wave_sum_bcast(s1);
  s2 = wave_sum_bcast(s2);
  s3 = wave_sum_bcast(s3);
  s4 = wave_sum_bcast(s4);
  s0 *= scale; s1 *= scale; s2 *= scale;
  s3 *= scale * m3;  // masked scores -> exact 0 (R5-exact placement)
  s4 *= scale * m4;

  float pv = s0;
  pv = (lane == 1) ? s1 : pv;
  pv = (lane == 2) ? s2 : pv;
  pv = (lane == 3) ? s3 : pv;
  pv = (lane == 4) ? s4 : pv;
  if (lane < 5) red[t & 1][lane][w] = pv;

  asm volatile("s_waitcnt lgkmcnt(0)" ::: "memory");
  __builtin_amdgcn_sched_barrier(0);
  __builtin_amdgcn_s_barrier();   // raw: no compiler vmcnt(0) drain
  __builtin_amdgcn_sched_barrier(0);

  // ---- full scores + softmax (R5-exact) ----
  float fs[5];
#pragma unroll
  for (int j = 0; j < 5; j++) {
    float4 rv = *(const float4*)(&red[t & 1][j][0]);
    fs[j] = (rv.x + rv.y) + (rv.z + rv.w);
  }
  float mx = fmaxf(fmaxf(fmaxf(fs[0], fs[1]), fmaxf(fs[2], fs[3])), fs[4]);
  float e0 = __expf(fs[0] - mx), e1 = __expf(fs[1] - mx), e2 = __expf(fs[2] - mx);
  float e3 = __expf(fs[3] - mx), e4 = __expf(fs[4] - mx);
  float inv = __fdividef(1.0f, e0 + e1 + e2 + e3 + e4);
  float q0 = e0 * inv, q1 = e1 * inv, q2 = e2 * inv;
  float q3 = e3 * inv * m3, q4 = e4 * inv * m4;  // padded rows contribute 0

  // ---- weighted sums, gate, state update (R5-exact fma chains) ----
  float ax = q0 * ow[S0].x; ax = fmaf(q1, ow[S1].x, ax); ax = fmaf(q2, ow[S2].x, ax);
  ax = fmaf(q3, ow[S3].x, ax); ax = fmaf(q4, ow[S4].x, ax);
  float ay = q0 * ow[S0].y; ay = fmaf(q1, ow[S1].y, ay); ay = fmaf(q2, ow[S2].y, ay);
  ay = fmaf(q3, ow[S3].y, ay); ay = fmaf(q4, ow[S4].y, ay);
  float gx = q0 * gw[S0].x; gx = fmaf(q1, gw[S1].x, gx); gx = fmaf(q2, gw[S2].x, gx);
  gx = fmaf(q3, gw[S3].x, gx); gx = fmaf(q4, gw[S4].x, gx);
  float gy = q0 * gw[S0].y; gy = fmaf(q1, gw[S1].y, gy); gy = fmaf(q2, gw[S2].y, gy);
  gy = fmaf(q3, gw[S3].y, gy); gy = fmaf(q4, gw[S4].y, gy);

  float2 ot;
  ot.x = fmaf(ax, __fdividef(1.f, 1.f + __expf(-(pg[SLOT].x + gx))), pm[SLOT].x);
  ot.y = fmaf(ay, __fdividef(1.f, 1.f + __expf(-(pg[SLOT].y + gy))), pm[SLOT].y);
  st = ot;
  *(float2*)(po + (size_t)t * Dq + dbase) = ot;
}

// ===========================================================================
// FUSED kernel: blocks 0..7 = per-batch 4-wave scans; blocks 8.. = GEMM
// producers in band-major order publishing done[b*16+band] (12 tiles/band).
// ===========================================================================
__global__ __launch_bounds__(256, 1) void fused_kernel(
    const float* __restrict__ O,
    const ushort* __restrict__ Ohi, const ushort* __restrict__ Olo,
    const ushort* __restrict__ Wmh, const ushort* __restrict__ Wml,
    const ushort* __restrict__ Wgh, const ushort* __restrict__ Wgl,
    const float* __restrict__ bm, const float* __restrict__ bg,
    float* __restrict__ Pg, float* __restrict__ Gm,
    float* __restrict__ out, int* __restrict__ done) {
  __shared__ __align__(16) float red[2][5][4];  // score partials (scan only)

  if (blockIdx.x < 8) {
    // ---------------- scan: 4 waves, wave w owns dims [128w,128w+128) ------
    int b = blockIdx.x;
    int tid = threadIdx.x;
    int w = tid >> 6;
    int lane = tid & 63;
    int dbase = w * 128 + lane * 2;
    int bb = b * 16;
    const float* ob  = O   + (size_t)b * Tq * Dq;
    const float* Gb  = Gm  + (size_t)b * Tq * Dq;
    const float* Pgb = Pg  + (size_t)b * Tq * Dq;
    const float* pmb = out + (size_t)b * Tq * Dq;  // PRE_mlp lives in d_out
    float* po = out + (size_t)b * Tq * Dq;

    int bandReady = -1;
    wait_band(done, bb + 0, 12);
    bandReady = 0;
    __builtin_amdgcn_sched_barrier(0);

    float2 ow[8], gw[8], pm[8], pg[8];
    float2 st = make_float2(0.f, 0.f);
#pragma unroll
    for (int r = 0; r < 5; r++) {
      ow[r] = *(const float2*)(ob  + (size_t)r * Dq + dbase);
      gw[r] = *(const float2*)(Gb  + (size_t)r * Dq + dbase);
      pm[r] = *(const float2*)(pmb + (size_t)r * Dq + dbase);
      pg[r] = *(const float2*)(Pgb + (size_t)r * Dq + dbase);
    }

#define SS(t_, m3_, m4_, A,B,C,D,E, SL_, LW_)                                  \
    scan_step4<A,B,C,D,E, SL_, LW_>(t_, m3_, m4_, lane, w, dbase, ob, Gb,      \
        Pgb, pmb, po, red, done, bb, bandReady, ow, gw, pm, pg, st)

    SS(0, 0.f, 0.f, 0,1,2,3,4, 0, 5);
    SS(1, 1.f, 0.f, 0,1,2,3,4, 1, 6);
    for (int tb = 2; tb <= 2034; tb += 8) {
      SS(tb+0, 1.f, 1.f, 0,1,2,3,4, 2, 7);
      SS(tb+1, 1.f, 1.f, 1,2,3,4,5, 3, 0);
      SS(tb+2, 1.f, 1.f, 2,3,4,5,6, 4, 1);
      SS(tb+3, 1.f, 1.f, 3,4,5,6,7, 5, 2);
      SS(tb+4, 1.f, 1.f, 4,5,6,7,0, 6, 3);
      SS(tb+5, 1.f, 1.f, 5,6,7,0,1, 7, 4);
      SS(tb+6, 1.f, 1.f, 6,7,0,1,2, 0, 5);
      SS(tb+7, 1.f, 1.f, 7,0,1,2,3, 1, 6);
    }
    SS(2042, 1.f, 1.f, 0,1,2,3,4, 2, 7);
    SS(2043, 1.f, 1.f, 1,2,3,4,5, 3, 0);
    SS(2044, 1.f, 1.f, 2,3,4,5,6, 4, 1);
    SS(2045, 1.f, 1.f, 3,4,5,6,7, 5, 2);
    SS(2046, 1.f, 0.f, 4,5,6,7,0, 6, 3);
    SS(2047, 0.f, 0.f, 5,6,7,0,1, 7, 4);
#undef SS
    return;
  }

  // ---------------- GEMM producer (R12/R13-verified split-f16) -------------
  int g = blockIdx.x - 8;
  int band = g / 96;
  int rem = g % 96;
  int bat = rem / 12;
  int role = rem % 12;            // 0..7: mode0 by=role; 8..11: mode1 by=role-8
  int bt0 = (bat * 16 + band) * 128;
  int gb = bat * Tq;
  int t0 = bt0 % Tq;

  int tid = threadIdx.x;
  int l = tid & 63, w = tid >> 6;
  int wm = w >> 1, wn = w & 1;
  int r16 = l & 15, kg = l >> 4;

  f32x4 acc[4][4] = {};
  const f16x8 zz = {0, 0, 0, 0, 0, 0, 0, 0};

  if (role >= 8) {
    // ---- MODE 1: G = O @ Wg[:, 2560:]^T ----
    int by = role - 8;
    const ushort *bph[4], *bpl[4];
    int ncol[4];
#pragma unroll
    for (int ni = 0; ni < 4; ni++) {
      int n_g = by * 128 + wn * 64 + ni * 16 + r16;
      ncol[ni] = n_g;
      size_t off = (size_t)n_g * 3072 + 2560 + kg * 8;
      bph[ni] = Wgh + off; bpl[ni] = Wgl + off;
    }
    const ushort *aph[4], *apl[4];
#pragma unroll
    for (int mi = 0; mi < 4; mi++) {
      size_t off = (size_t)(bt0 + wm * 64 + mi * 16 + r16) * Dq + kg * 8;
      aph[mi] = Ohi + off; apl[mi] = Olo + off;
    }
#pragma unroll 4
    for (int ks = 0; ks < 16; ks++) {
      f16x8 Ah[4], Al[4], Bh[4], Bl[4];
#pragma unroll
      for (int mi = 0; mi < 4; mi++) {
        Ah[mi] = *(const f16x8*)aph[mi]; aph[mi] += 32;
        Al[mi] = *(const f16x8*)apl[mi]; apl[mi] += 32;
      }
#pragma unroll
      for (int ni = 0; ni < 4; ni++) {
        Bh[ni] = *(const f16x8*)bph[ni]; bph[ni] += 32;
        Bl[ni] = *(const f16x8*)bpl[ni]; bpl[ni] += 32;
      }
#pragma unroll
      for (int mi = 0; mi < 4; mi++)
#pragma unroll
        for (int ni = 0; ni < 4; ni++) {
          acc[mi][ni] = __builtin_amdgcn_mfma_f32_16x16x32_f16(Ah[mi], Bh[ni], acc[mi][ni], 0, 0, 0);
          acc[mi][ni] = __builtin_amdgcn_mfma_f32_16x16x32_f16(Al[mi], Bh[ni], acc[mi][ni], 0, 0, 0);
          acc[mi][ni] = __builtin_amdgcn_mfma_f32_16x16x32_f16(Ah[mi], Bl[ni], acc[mi][ni], 0, 0, 0);
        }
    }
    const float SC = 1.0f / 65536.0f;
#pragma unroll
    for (int ni = 0; ni < 4; ni++) {
#pragma unroll
      for (int mi = 0; mi < 4; mi++) {
        int rowb = bt0 + wm * 64 + mi * 16 + kg * 4;
#pragma unroll
        for (int rr = 0; rr < 4; rr++)
          Gm[(size_t)(rowb + rr) * Dq + ncol[ni]] = acc[mi][ni][rr] * SC;
      }
    }
  } else {
    // ---- MODE 0: PRE = windowflat @ {Wm | Wg[:, :2560]}^T + bias ----
    int by = role;
    const ushort *bph[4], *bpl[4];
    int ncol[4];
#pragma unroll
    for (int ni = 0; ni < 4; ni++) {
      int n_g = by * 128 + wn * 64 + ni * 16 + r16;
      ncol[ni] = n_g;
      size_t off;
      if (by < 4) { off = (size_t)n_g * 2560 + kg * 8; bph[ni] = Wmh + off; bpl[ni] = Wml + off; }
      else { off = (size_t)(n_g - 512) * 3072 + kg * 8; bph[ni] = Wgh + off; bpl[ni] = Wgl + off; }
    }
    int arow[4][5];
    uint vmask[4];
#pragma unroll
    for (int mi = 0; mi < 4; mi++) {
      int t = t0 + wm * 64 + mi * 16 + r16;
      int sh = 2 - t; if (sh < 0) sh = 0;
      int hi2 = t + 2; if (hi2 > Tq - 1) hi2 = Tq - 1;
      int lo2 = t - 2; if (lo2 < 0) lo2 = 0;
      int nv = hi2 - lo2 + 1;
      uint vm = 0;
#pragma unroll
      for (int j = 0; j < 5; j++) {
        int r = t - 2 + j + sh;
        if (r > Tq - 1) r = Tq - 1;
        arow[mi][j] = gb + r;
        if (j < nv) vm |= (1u << j);
      }
      vmask[mi] = vm;
    }
#pragma unroll
    for (int j = 0; j < 5; j++) {
      const ushort *aph[4], *apl[4];
      bool v[4];
#pragma unroll
      for (int mi = 0; mi < 4; mi++) {
        size_t off = (size_t)arow[mi][j] * Dq + kg * 8;
        aph[mi] = Ohi + off; apl[mi] = Olo + off;
        v[mi] = (vmask[mi] >> j) & 1u;
      }
#pragma unroll 4
      for (int ks = 0; ks < 16; ks++) {
        f16x8 Ah[4], Al[4], Bh[4], Bl[4];
#pragma unroll
        for (int mi = 0; mi < 4; mi++) {
          f16x8 th = *(const f16x8*)aph[mi]; aph[mi] += 32;
          f16x8 tl = *(const f16x8*)apl[mi]; apl[mi] += 32;
          Ah[mi] = v[mi] ? th : zz;
          Al[mi] = v[mi] ? tl : zz;
        }
#pragma unroll
        for (int ni = 0; ni < 4; ni++) {
          Bh[ni] = *(const f16x8*)bph[ni]; bph[ni] += 32;
          Bl[ni] = *(const f16x8*)bpl[ni]; bpl[ni] += 32;
        }
#pragma unroll
        for (int mi = 0; mi < 4; mi++)
#pragma unroll
          for (int ni = 0; ni < 4; ni++) {
            acc[mi][ni] = __builtin_amdgcn_mfma_f32_16x16x32_f16(Ah[mi], Bh[ni], acc[mi][ni], 0, 0, 0);
            acc[mi][ni] = __builtin_amdgcn_mfma_f32_16x16x32_f16(Al[mi], Bh[ni], acc[mi][ni], 0, 0, 0);
            acc[mi][ni] = __builtin_amdgcn_mfma_f32_16x16x32_f16(Ah[mi], Bl[ni], acc[mi][ni], 0, 0, 0);
          }
      }
    }
    const float SC = 1.0f / 65536.0f;
    float* dst = (by < 4) ? out : Pg;  // PRE_mlp -> d_out, PRE_gate -> ws
    const float* bias = (by < 4) ? bm : bg;
#pragma unroll
    for (int ni = 0; ni < 4; ni++) {
      int oc = (by < 4) ? ncol[ni] : ncol[ni] - 512;
      float bi = bias[oc];
#pragma unroll
      for (int mi = 0; mi < 4; mi++) {
        int rowb = bt0 + wm * 64 + mi * 16 + kg * 4;
#pragma unroll
        for (int rr = 0; rr < 4; rr++)
          dst[(size_t)(rowb + rr) * Dq + oc] = fmaf(acc[mi][ni][rr], SC, bi);
      }
    }
  }

  // ---- publish: all stores visible, then bump the band counter ----
  __threadfence();
  __syncthreads();
  if (tid == 0) {
    __hip_atomic_fetch_add(&done[bat * 16 + band], 1, __ATOMIC_RELEASE,
                           __HIP_MEMORY_SCOPE_AGENT);
  }
}

// ---------------------------------------------------------------------------
// f32 fallback (ws too small) — R1-verified serial GEMM + 4-wave scan.
// ---------------------------------------------------------------------------
__global__ __launch_bounds__(256) void gemm_pre(
    const float* __restrict__ O, const float* __restrict__ Wm,
    const float* __restrict__ Wg, const float* __restrict__ bm,
    const float* __restrict__ bg, float* __restrict__ Pm,
    float* __restrict__ Pg, float* __restrict__ Gm, int mode) {
  const int BM = 128, BN = 128, BK = 16;
  __shared__ float As[BK][132];
  __shared__ float Bs[BK][132];
  int tidx = threadIdx.x;
  int bt0 = blockIdx.x * BM;
  int b = bt0 / Tq;
  int t0 = bt0 % Tq;
  int n0 = blockIdx.y * BN;
  int K = mode ? Dq : 5 * Dq;
  int tx = tidx % 16, ty = tidx / 16, lr = tidx >> 2, lc = (tidx & 3) * 4;
  float acc[8][8];
#pragma unroll
  for (int i = 0; i < 8; i++)
#pragma unroll
    for (int j = 0; j < 8; j++) acc[i][j] = 0.f;
  for (int kb = 0; kb < K; kb += BK) {
#pragma unroll
    for (int h = 0; h < 2; h++) {
      int m = lr + h * 64;
      int t = t0 + m;
      float4 av;
      if (mode == 0) {
        int j = kb >> 9;
        int kcol = (kb & 511) + lc;
        int sh = 2 - t; if (sh < 0) sh = 0;
        int r = t - 2 + j + sh;
        int hi = t + 2; if (hi > Tq - 1) hi = Tq - 1;
        int lo2 = t - 2; if (lo2 < 0) lo2 = 0;
        int nv = hi - lo2 + 1;
        if (j < nv) av = *reinterpret_cast<const float4*>(O + ((size_t)b * Tq + r) * Dq + kcol);
        else av = make_float4(0.f, 0.f, 0.f, 0.f);
      } else {
        av = *reinterpret_cast<const float4*>(O + ((size_t)b * Tq + t) * Dq + kb + lc);
      }
      As[lc + 0][m] = av.x; As[lc + 1][m] = av.y;
      As[lc + 2][m] = av.z; As[lc + 3][m] = av.w;
    }
#pragma unroll
    for (int h = 0; h < 2; h++) {
      int n = lr + h * 64;
      int gn = n0 + n;
      const float* wrow;
      int col;
      if (mode == 0) {
        if (gn < 512) { wrow = Wm + (size_t)gn * 2560; col = kb + lc; }
        else          { wrow = Wg + (size_t)(gn - 512) * 3072; col = kb + lc; }
      } else {
        wrow = Wg + (size_t)gn * 3072; col = 2560 + kb + lc;
      }
      float4 bv = *reinterpret_cast<const float4*>(wrow + col);
      Bs[lc + 0][n] = bv.x; Bs[lc + 1][n] = bv.y;
      Bs[lc + 2][n] = bv.z; Bs[lc + 3][n] = bv.w;
    }
    __syncthreads();
#pragma unroll
    for (int kk = 0; kk < BK; kk++) {
      float a[8], bb[8];
      float4 a0 = *reinterpret_cast<float4*>(&As[kk][ty * 8]);
      float4 a1 = *reinterpret_cast<float4*>(&As[kk][ty * 8 + 4]);
      float4 b0 = *reinterpret_cast<float4*>(&Bs[kk][tx * 8]);
      float4 b1 = *reinterpret_cast<float4*>(&Bs[kk][tx * 8 + 4]);
      a[0]=a0.x; a[1]=a0.y; a[2]=a0.z; a[3]=a0.w; a[4]=a1.x; a[5]=a1.y; a[6]=a1.z; a[7]=a1.w;
      bb[0]=b0.x; bb[1]=b0.y; bb[2]=b0.z; bb[3]=b0.w; bb[4]=b1.x; bb[5]=b1.y; bb[6]=b1.z; bb[7]=b1.w;
#pragma unroll
      for (int i = 0; i < 8; i++)
#pragma unroll
        for (int j = 0; j < 8; j++) acc[i][j] = fmaf(a[i], bb[j], acc[i][j]);
    }
    __syncthreads();
  }
  int gn = n0 + tx * 8;
  float bias[8];
  float* dstbase;
  int coloff;
  if (mode == 0) {
    if (gn < 512) {
#pragma unroll
      for (int j = 0; j < 8; j++) bias[j] = bm[gn + j];
      dstbase = Pm; coloff = gn;
    } else {
#pragma unroll
      for (int j = 0; j < 8; j++) bias[j] = bg[gn - 512 + j];
      dstbase = Pg; coloff = gn - 512;
    }
  } else {
#pragma unroll
    for (int j = 0; j < 8; j++) bias[j] = 0.f;
    dstbase = Gm; coloff = gn;
  }
#pragma unroll
  for (int i = 0; i < 8; i++) {
    int bt = bt0 + ty * 8 + i;
    float4 v0 = make_float4(acc[i][0] + bias[0], acc[i][1] + bias[1],
                            acc[i][2] + bias[2], acc[i][3] + bias[3]);
    float4 v1 = make_float4(acc[i][4] + bias[4], acc[i][5] + bias[5],
                            acc[i][6] + bias[6], acc[i][7] + bias[7]);
    float4* d = reinterpret_cast<float4*>(dstbase + (size_t)bt * Dq + coloff);
    d[0] = v0;
    d[1] = v1;
  }
}

// Fallback serial 4-wave scan (done[] pre-filled to 12 so gates are no-ops).
__global__ __launch_bounds__(256, 1) void scan_only(
    const float* __restrict__ O, const float* __restrict__ Gm,
    const float* __restrict__ Pg, const float* __restrict__ Pm,
    float* __restrict__ out, int* __restrict__ done) {
  __shared__ __align__(16) float red[2][5][4];
  int b = blockIdx.x;
  int tid = threadIdx.x;
  int w = tid >> 6;
  int lane = tid & 63;
  int dbase = w * 128 + lane * 2;
  int bb = b * 16;
  const float* ob  = O  + (size_t)b * Tq * Dq;
  const float* Gb  = Gm + (size_t)b * Tq * Dq;
  const float* Pgb = Pg + (size_t)b * Tq * Dq;
  const float* pmb = Pm + (size_t)b * Tq * Dq;
  float* po = out + (size_t)b * Tq * Dq;
  int bandReady = 15;

  float2 ow[8], gw[8], pm[8], pg[8];
  float2 st = make_float2(0.f, 0.f);
#pragma unroll
  for (int r = 0; r < 5; r++) {
    ow[r] = *(const float2*)(ob  + (size_t)r * Dq + dbase);
    gw[r] = *(const float2*)(Gb  + (size_t)r * Dq + dbase);
    pm[r] = *(const float2*)(pmb + (size_t)r * Dq + dbase);
    pg[r] = *(const float2*)(Pgb + (size_t)r * Dq + dbase);
  }
#define SS(t_, m3_, m4_, A,B,C,D,E, SL_, LW_)                                  \
  scan_step4<A,B,C,D,E, SL_, LW_>(t_, m3_, m4_, lane, w, dbase, ob, Gb,        \
      Pgb, pmb, po, red, done, bb, bandReady, ow, gw, pm, pg, st)
  SS(0, 0.f, 0.f, 0,1,2,3,4, 0, 5);
  SS(1, 1.f, 0.f, 0,1,2,3,4, 1, 6);
  for (int tb = 2; tb <= 2034; tb += 8) {
    SS(tb+0, 1.f, 1.f, 0,1,2,3,4, 2, 7);
    SS(tb+1, 1.f, 1.f, 1,2,3,4,5, 3, 0);
    SS(tb+2, 1.f, 1.f, 2,3,4,5,6, 4, 1);
    SS(tb+3, 1.f, 1.f, 3,4,5,6,7, 5, 2);
    SS(tb+4, 1.f, 1.f, 4,5,6,7,0, 6, 3);
    SS(tb+5, 1.f, 1.f, 5,6,7,0,1, 7, 4);
    SS(tb+6, 1.f, 1.f, 6,7,0,1,2, 0, 5);
    SS(tb+7, 1.f, 1.f, 7,0,1,2,3, 1, 6);
  }
  SS(2042, 1.f, 1.f, 0,1,2,3,4, 2, 7);
  SS(2043, 1.f, 1.f, 1,2,3,4,5, 3, 0);
  SS(2044, 1.f, 1.f, 2,3,4,5,6, 4, 1);
  SS(2045, 1.f, 1.f, 3,4,5,6,7, 5, 2);
  SS(2046, 1.f, 0.f, 4,5,6,7,0, 6, 3);
  SS(2047, 0.f, 0.f, 5,6,7,0,1, 7, 4);
#undef SS
}

extern "C" void kernel_launch(void* const* d_in, const int* in_sizes, int n_in,
                              void* d_out, int out_size, void* d_ws, size_t ws_size,
                              hipStream_t stream) {
  const float* O  = (const float*)d_in[0];
  const float* Wm = (const float*)d_in[1];
  const float* bm = (const float*)d_in[2];
  const float* Wg = (const float*)d_in[3];
  const float* bg = (const float*)d_in[4];
  float* out = (float*)d_out;

  const size_t NTOT = (size_t)Bq * Tq * Dq;   // 8.39M
  const size_t NWM = 512 * 2560, NWG = 512 * 3072;
  float* Pg = (float*)d_ws;
  float* Gm = Pg + NTOT;
  ushort* OHI = (ushort*)(Gm + NTOT);
  ushort* OLO = OHI + NTOT;
  ushort* WMH = OLO + NTOT;
  ushort* WML = WMH + NWM;
  ushort* WGH = WML + NWM;
  ushort* WGL = WGH + NWG;
  int* done = (int*)(WGL + NWG);              // 128 ints

  size_t need = 2 * NTOT * 4 + 2 * (NTOT + NWM + NWG) * 2 + 128 * 4;
  if (ws_size >= need) {
    hipMemsetAsync(done, 0, 128 * 4, stream);
    cvt_f16split<<<dim3((NTOT / 8 + 255) / 256), dim3(256), 0, stream>>>(O, OHI, OLO, NTOT / 8);
    cvt_f16split<<<dim3((NWM / 8 + 255) / 256), dim3(256), 0, stream>>>(Wm, WMH, WML, NWM / 8);
    cvt_f16split<<<dim3((NWG / 8 + 255) / 256), dim3(256), 0, stream>>>(Wg, WGH, WGL, NWG / 8);
    fused_kernel<<<dim3(8 + 16 * 96), dim3(256), 0, stream>>>(
        O, OHI, OLO, WMH, WML, WGH, WGL, bm, bg, Pg, Gm, out, done);
  } else {
    bool sep = ws_size >= (size_t)(3 * NTOT * 4 + 128 * 4);
    float* Pm = sep ? (Gm + NTOT) : out;
    int* done2 = sep ? (int*)(Pm + NTOT) : (int*)(Gm + NTOT);
    hipMemsetAsync(done2, 12, 128 * 4, stream);  // every byte 12 -> >= 12
    gemm_pre<<<dim3(128, 8), dim3(256), 0, stream>>>(O, Wm, Wg, bm, bg, Pm, Pg, Gm, 0);
    gemm_pre<<<dim3(128, 4), dim3(256), 0, stream>>>(O, Wm, Wg, bm, bg, Pm, Pg, Gm, 1);
    scan_only<<<dim3(Bq), dim3(256), 0, stream>>>(O, Gm, Pg, Pm, out, done2);
  }
}

// Round 16
// 1524.775 us; speedup vs baseline: 2.2744x; 1.1665x over previous
//
#include <hip/hip_runtime.h>

#define Bq 8
#define Tq 2048
#define Dq 512

typedef __attribute__((ext_vector_type(8))) _Float16 f16x8;  // 8 f16 = 4 VGPRs
typedef __attribute__((ext_vector_type(8))) short u16x8;
typedef __attribute__((ext_vector_type(4))) float f32x4;

// ---------------------------------------------------------------------------
// f32 -> (hi,lo) f16 split planes, x*256 pre-scale (undone by 2^-16 in GEMM).
// Used only for the (small, reused) weight matrices.
// ---------------------------------------------------------------------------
__global__ __launch_bounds__(256) void cvt_f16split(
    const float* __restrict__ s, ushort* __restrict__ hi,
    ushort* __restrict__ lo, int n8) {
  int i = blockIdx.x * 256 + threadIdx.x;
  if (i >= n8) return;
  const float4* sp = reinterpret_cast<const float4*>(s) + i * 2;
  float4 a = sp[0], b = sp[1];
  float x[8] = {a.x, a.y, a.z, a.w, b.x, b.y, b.z, b.w};
  ushort h[8], l[8];
#pragma unroll
  for (int e = 0; e < 8; e++) {
    float xs = x[e] * 256.0f;
    _Float16 hh = (_Float16)xs;
    _Float16 ll = (_Float16)(xs - (float)hh);
    h[e] = *(ushort*)&hh;
    l[e] = *(ushort*)&ll;
  }
  *reinterpret_cast<u16x8*>(hi + (size_t)i * 8) = *reinterpret_cast<u16x8*>(h);
  *reinterpret_cast<u16x8*>(lo + (size_t)i * 8) = *reinterpret_cast<u16x8*>(l);
}

// In-register split of 8 f32 (two float4) into hi/lo f16x8 planes — the SAME
// elementwise math as cvt_f16split, so PRE results are bit-identical to the
// precomputed-OHI/OLO variant (R15-verified, absmax 0.0078).
__device__ __forceinline__ void split8(const float4& a, const float4& b,
                                       f16x8& hi, f16x8& lo) {
  float x[8] = {a.x, a.y, a.z, a.w, b.x, b.y, b.z, b.w};
#pragma unroll
  for (int e = 0; e < 8; e++) {
    float xs = x[e] * 256.0f;
    _Float16 hh = (_Float16)xs;
    _Float16 ll = (_Float16)(xs - (float)hh);
    hi[e] = hh;
    lo[e] = ll;
  }
}

// ===========================================================================
// Common helpers.
// ===========================================================================
template <int CTRL>
__device__ __forceinline__ float dppadd(float v) {
  int r = __builtin_amdgcn_update_dpp(0, __float_as_int(v), CTRL, 0xF, 0xF, true);
  return v + __int_as_float(r);
}
__device__ __forceinline__ float wave_sum_bcast(float v) {
  v = dppadd<0x111>(v);
  v = dppadd<0x112>(v);
  v = dppadd<0x114>(v);
  v = dppadd<0x118>(v);
  v = dppadd<0x142>(v);
  v = dppadd<0x143>(v);
  return __int_as_float(__builtin_amdgcn_readlane(__float_as_int(v), 63));
}

// Bounded agent-scope wait on a monotone counter (bug -> absmax fail, not hang).
__device__ __forceinline__ void wait_band(int* done, int idx, int target) {
  int it = 0;
  while (__hip_atomic_load(&done[idx], __ATOMIC_ACQUIRE,
                           __HIP_MEMORY_SCOPE_AGENT) < target) {
    __builtin_amdgcn_s_sleep(8);
    if (++it > (1 << 22)) break;
  }
}

// ===========================================================================
// 4-wave cooperative scan step — R15-verified (absmax 0.0078). NUMERICS ARE
// R5's EXACT ORDER (mul-then-fma partials, per-wave scale+mask before
// publish, fma-chain weighted sums). Do not re-derive (R14 lesson: ulp-level
// reordering diverges chaotically, 0.195 fail).
// ===========================================================================
template <int S0, int S1, int S2, int S3, int S4, int SLOT, int SLW>
__device__ __forceinline__ void scan_step4(
    int t, float m3, float m4, int lane, int w, int dbase,
    const float* __restrict__ ob, const float* __restrict__ Gb,
    const float* __restrict__ Pgb, const float* __restrict__ pmb,
    float* __restrict__ po, float (*red)[5][4],
    int* done, int bb, int& bandReady,
    float2 (&ow)[8], float2 (&gw)[8], float2 (&pm)[8], float2 (&pg)[8],
    float2& st) {
  int rw = t + 5; if (rw > Tq - 1) rw = Tq - 1;
  int band = rw >> 7;
  if (band > bandReady) {  // once per 128 steps: gate on producer progress
    wait_band(done, bb + band, 12);
    bandReady = band;
  }
  __builtin_amdgcn_sched_barrier(0);
  ow[SLW] = *(const float2*)(ob  + (size_t)rw * Dq + dbase);
  gw[SLW] = *(const float2*)(Gb  + (size_t)rw * Dq + dbase);
  pm[SLW] = *(const float2*)(pmb + (size_t)rw * Dq + dbase);
  pg[SLW] = *(const float2*)(Pgb + (size_t)rw * Dq + dbase);
  __builtin_amdgcn_sched_barrier(0);

  // ---- partial scores over this wave's 128 dims (R5-exact) ----
  const float scale = 0.04419417382415922f;  // 1/sqrt(512)
  float s0 = st.x * ow[S0].x; s0 = fmaf(st.y, ow[S0].y, s0);
  float s1 = st.x * ow[S1].x; s1 = fmaf(st.y, ow[S1].y, s1);
  float s2 = st.x * ow[S2].x; s2 = fmaf(st.y, ow[S2].y, s2);
  float s3 = st.x * ow[S3].x; s3 = fmaf(st.y, ow[S3].y, s3);
  float s4 = st.x * ow[S4].x; s4 = fmaf(st.y, ow[S4].y, s4);
  s0 = wave_sum_bcast(s0);
  s1 = wave_sum_bcast(s1);
  s2 = wave_sum_bcast(s2);
  s3 = wave_sum_bcast(s3);
  s4 = wave_sum_bcast(s4);
  s0 *= scale; s1 *= scale; s2 *= scale;
  s3 *= scale * m3;  // masked scores -> exact 0
  s4 *= scale * m4;

  float pv = s0;
  pv = (lane == 1) ? s1 : pv;
  pv = (lane == 2) ? s2 : pv;
  pv = (lane == 3) ? s3 : pv;
  pv = (lane == 4) ? s4 : pv;
  if (lane < 5) red[t & 1][lane][w] = pv;

  asm volatile("s_waitcnt lgkmcnt(0)" ::: "memory");
  __builtin_amdgcn_sched_barrier(0);
  __builtin_amdgcn_s_barrier();   // raw: no compiler vmcnt(0) drain
  __builtin_amdgcn_sched_barrier(0);

  // ---- full scores + softmax (R5-exact) ----
  float fs[5];
#pragma unroll
  for (int j = 0; j < 5; j++) {
    float4 rv = *(const float4*)(&red[t & 1][j][0]);
    fs[j] = (rv.x + rv.y) + (rv.z + rv.w);
  }
  float mx = fmaxf(fmaxf(fmaxf(fs[0], fs[1]), fmaxf(fs[2], fs[3])), fs[4]);
  float e0 = __expf(fs[0] - mx), e1 = __expf(fs[1] - mx), e2 = __expf(fs[2] - mx);
  float e3 = __expf(fs[3] - mx), e4 = __expf(fs[4] - mx);
  float inv = __fdividef(1.0f, e0 + e1 + e2 + e3 + e4);
  float q0 = e0 * inv, q1 = e1 * inv, q2 = e2 * inv;
  float q3 = e3 * inv * m3, q4 = e4 * inv * m4;  // padded rows contribute 0

  // ---- weighted sums, gate, state update (R5-exact fma chains) ----
  float ax = q0 * ow[S0].x; ax = fmaf(q1, ow[S1].x, ax); ax = fmaf(q2, ow[S2].x, ax);
  ax = fmaf(q3, ow[S3].x, ax); ax = fmaf(q4, ow[S4].x, ax);
  float ay = q0 * ow[S0].y; ay = fmaf(q1, ow[S1].y, ay); ay = fmaf(q2, ow[S2].y, ay);
  ay = fmaf(q3, ow[S3].y, ay); ay = fmaf(q4, ow[S4].y, ay);
  float gx = q0 * gw[S0].x; gx = fmaf(q1, gw[S1].x, gx); gx = fmaf(q2, gw[S2].x, gx);
  gx = fmaf(q3, gw[S3].x, gx); gx = fmaf(q4, gw[S4].x, gx);
  float gy = q0 * gw[S0].y; gy = fmaf(q1, gw[S1].y, gy); gy = fmaf(q2, gw[S2].y, gy);
  gy = fmaf(q3, gw[S3].y, gy); gy = fmaf(q4, gw[S4].y, gy);

  float2 ot;
  ot.x = fmaf(ax, __fdividef(1.f, 1.f + __expf(-(pg[SLOT].x + gx))), pm[SLOT].x);
  ot.y = fmaf(ay, __fdividef(1.f, 1.f + __expf(-(pg[SLOT].y + gy))), pm[SLOT].y);
  st = ot;
  *(float2*)(po + (size_t)t * Dq + dbase) = ot;
}

// ===========================================================================
// FUSED kernel: blocks 0..7 = per-batch 4-wave scans; blocks 8.. = GEMM
// producers (band-major, done[b*16+band], 12 tiles/band). Producers now read
// f32 O directly and split to hi/lo f16 IN-REGISTER (bit-identical math to
// the old cvt_f16split pass) — removes the 60us cvt_O dispatch from the
// critical path and 67 MB of OHI/OLO traffic.
// ===========================================================================
__global__ __launch_bounds__(256, 1) void fused_kernel(
    const float* __restrict__ O,
    const ushort* __restrict__ Wmh, const ushort* __restrict__ Wml,
    const ushort* __restrict__ Wgh, const ushort* __restrict__ Wgl,
    const float* __restrict__ bm, const float* __restrict__ bg,
    float* __restrict__ Pg, float* __restrict__ Gm,
    float* __restrict__ out, int* __restrict__ done) {
  __shared__ __align__(16) float red[2][5][4];  // score partials (scan only)

  if (blockIdx.x < 8) {
    // ---------------- scan: 4 waves, wave w owns dims [128w,128w+128) ------
    int b = blockIdx.x;
    int tid = threadIdx.x;
    int w = tid >> 6;
    int lane = tid & 63;
    int dbase = w * 128 + lane * 2;
    int bb = b * 16;
    const float* ob  = O   + (size_t)b * Tq * Dq;
    const float* Gb  = Gm  + (size_t)b * Tq * Dq;
    const float* Pgb = Pg  + (size_t)b * Tq * Dq;
    const float* pmb = out + (size_t)b * Tq * Dq;  // PRE_mlp lives in d_out
    float* po = out + (size_t)b * Tq * Dq;

    int bandReady = -1;
    wait_band(done, bb + 0, 12);
    bandReady = 0;
    __builtin_amdgcn_sched_barrier(0);

    float2 ow[8], gw[8], pm[8], pg[8];
    float2 st = make_float2(0.f, 0.f);
#pragma unroll
    for (int r = 0; r < 5; r++) {
      ow[r] = *(const float2*)(ob  + (size_t)r * Dq + dbase);
      gw[r] = *(const float2*)(Gb  + (size_t)r * Dq + dbase);
      pm[r] = *(const float2*)(pmb + (size_t)r * Dq + dbase);
      pg[r] = *(const float2*)(Pgb + (size_t)r * Dq + dbase);
    }

#define SS(t_, m3_, m4_, A,B,C,D,E, SL_, LW_)                                  \
    scan_step4<A,B,C,D,E, SL_, LW_>(t_, m3_, m4_, lane, w, dbase, ob, Gb,      \
        Pgb, pmb, po, red, done, bb, bandReady, ow, gw, pm, pg, st)

    SS(0, 0.f, 0.f, 0,1,2,3,4, 0, 5);
    SS(1, 1.f, 0.f, 0,1,2,3,4, 1, 6);
    for (int tb = 2; tb <= 2034; tb += 8) {
      SS(tb+0, 1.f, 1.f, 0,1,2,3,4, 2, 7);
      SS(tb+1, 1.f, 1.f, 1,2,3,4,5, 3, 0);
      SS(tb+2, 1.f, 1.f, 2,3,4,5,6, 4, 1);
      SS(tb+3, 1.f, 1.f, 3,4,5,6,7, 5, 2);
      SS(tb+4, 1.f, 1.f, 4,5,6,7,0, 6, 3);
      SS(tb+5, 1.f, 1.f, 5,6,7,0,1, 7, 4);
      SS(tb+6, 1.f, 1.f, 6,7,0,1,2, 0, 5);
      SS(tb+7, 1.f, 1.f, 7,0,1,2,3, 1, 6);
    }
    SS(2042, 1.f, 1.f, 0,1,2,3,4, 2, 7);
    SS(2043, 1.f, 1.f, 1,2,3,4,5, 3, 0);
    SS(2044, 1.f, 1.f, 2,3,4,5,6, 4, 1);
    SS(2045, 1.f, 1.f, 3,4,5,6,7, 5, 2);
    SS(2046, 1.f, 0.f, 4,5,6,7,0, 6, 3);
    SS(2047, 0.f, 0.f, 5,6,7,0,1, 7, 4);
#undef SS
    return;
  }

  // ---------------- GEMM producer (split-f16, A from f32 O in-register) ----
  int g = blockIdx.x - 8;
  int band = g / 96;
  int rem = g % 96;
  int bat = rem / 12;
  int role = rem % 12;            // 0..7: mode0 by=role; 8..11: mode1 by=role-8
  int bt0 = (bat * 16 + band) * 128;
  int gb = bat * Tq;
  int t0 = bt0 % Tq;

  int tid = threadIdx.x;
  int l = tid & 63, w = tid >> 6;
  int wm = w >> 1, wn = w & 1;
  int r16 = l & 15, kg = l >> 4;

  f32x4 acc[4][4] = {};
  const f16x8 zz = {0, 0, 0, 0, 0, 0, 0, 0};

  if (role >= 8) {
    // ---- MODE 1: G = O @ Wg[:, 2560:]^T ----
    int by = role - 8;
    const ushort *bph[4], *bpl[4];
    int ncol[4];
#pragma unroll
    for (int ni = 0; ni < 4; ni++) {
      int n_g = by * 128 + wn * 64 + ni * 16 + r16;
      ncol[ni] = n_g;
      size_t off = (size_t)n_g * 3072 + 2560 + kg * 8;
      bph[ni] = Wgh + off; bpl[ni] = Wgl + off;
    }
    const float* ap[4];
#pragma unroll
    for (int mi = 0; mi < 4; mi++) {
      ap[mi] = O + (size_t)(bt0 + wm * 64 + mi * 16 + r16) * Dq + kg * 8;
    }
#pragma unroll 4
    for (int ks = 0; ks < 16; ks++) {
      f16x8 Ah[4], Al[4], Bh[4], Bl[4];
#pragma unroll
      for (int mi = 0; mi < 4; mi++) {
        float4 v0 = *(const float4*)ap[mi];
        float4 v1 = *(const float4*)(ap[mi] + 4);
        ap[mi] += 32;
        split8(v0, v1, Ah[mi], Al[mi]);
      }
#pragma unroll
      for (int ni = 0; ni < 4; ni++) {
        Bh[ni] = *(const f16x8*)bph[ni]; bph[ni] += 32;
        Bl[ni] = *(const f16x8*)bpl[ni]; bpl[ni] += 32;
      }
#pragma unroll
      for (int mi = 0; mi < 4; mi++)
#pragma unroll
        for (int ni = 0; ni < 4; ni++) {
          acc[mi][ni] = __builtin_amdgcn_mfma_f32_16x16x32_f16(Ah[mi], Bh[ni], acc[mi][ni], 0, 0, 0);
          acc[mi][ni] = __builtin_amdgcn_mfma_f32_16x16x32_f16(Al[mi], Bh[ni], acc[mi][ni], 0, 0, 0);
          acc[mi][ni] = __builtin_amdgcn_mfma_f32_16x16x32_f16(Ah[mi], Bl[ni], acc[mi][ni], 0, 0, 0);
        }
    }
    const float SC = 1.0f / 65536.0f;
#pragma unroll
    for (int ni = 0; ni < 4; ni++) {
#pragma unroll
      for (int mi = 0; mi < 4; mi++) {
        int rowb = bt0 + wm * 64 + mi * 16 + kg * 4;
#pragma unroll
        for (int rr = 0; rr < 4; rr++)
          Gm[(size_t)(rowb + rr) * Dq + ncol[ni]] = acc[mi][ni][rr] * SC;
      }
    }
  } else {
    // ---- MODE 0: PRE = windowflat @ {Wm | Wg[:, :2560]}^T + bias ----
    int by = role;
    const ushort *bph[4], *bpl[4];
    int ncol[4];
#pragma unroll
    for (int ni = 0; ni < 4; ni++) {
      int n_g = by * 128 + wn * 64 + ni * 16 + r16;
      ncol[ni] = n_g;
      size_t off;
      if (by < 4) { off = (size_t)n_g * 2560 + kg * 8; bph[ni] = Wmh + off; bpl[ni] = Wml + off; }
      else { off = (size_t)(n_g - 512) * 3072 + kg * 8; bph[ni] = Wgh + off; bpl[ni] = Wgl + off; }
    }
    int arow[4][5];
    uint vmask[4];
#pragma unroll
    for (int mi = 0; mi < 4; mi++) {
      int t = t0 + wm * 64 + mi * 16 + r16;
      int sh = 2 - t; if (sh < 0) sh = 0;
      int hi2 = t + 2; if (hi2 > Tq - 1) hi2 = Tq - 1;
      int lo2 = t - 2; if (lo2 < 0) lo2 = 0;
      int nv = hi2 - lo2 + 1;
      uint vm = 0;
#pragma unroll
      for (int j = 0; j < 5; j++) {
        int r = t - 2 + j + sh;
        if (r > Tq - 1) r = Tq - 1;
        arow[mi][j] = gb + r;
        if (j < nv) vm |= (1u << j);
      }
      vmask[mi] = vm;
    }
#pragma unroll
    for (int j = 0; j < 5; j++) {
      const float* ap[4];
      bool v[4];
#pragma unroll
      for (int mi = 0; mi < 4; mi++) {
        ap[mi] = O + (size_t)arow[mi][j] * Dq + kg * 8;
        v[mi] = (vmask[mi] >> j) & 1u;
      }
#pragma unroll 4
      for (int ks = 0; ks < 16; ks++) {
        f16x8 Ah[4], Al[4], Bh[4], Bl[4];
#pragma unroll
        for (int mi = 0; mi < 4; mi++) {
          float4 v0 = *(const float4*)ap[mi];
          float4 v1 = *(const float4*)(ap[mi] + 4);
          ap[mi] += 32;
          f16x8 th, tl;
          split8(v0, v1, th, tl);
          Ah[mi] = v[mi] ? th : zz;
          Al[mi] = v[mi] ? tl : zz;
        }
#pragma unroll
        for (int ni = 0; ni < 4; ni++) {
          Bh[ni] = *(const f16x8*)bph[ni]; bph[ni] += 32;
          Bl[ni] = *(const f16x8*)bpl[ni]; bpl[ni] += 32;
        }
#pragma unroll
        for (int mi = 0; mi < 4; mi++)
#pragma unroll
          for (int ni = 0; ni < 4; ni++) {
            acc[mi][ni] = __builtin_amdgcn_mfma_f32_16x16x32_f16(Ah[mi], Bh[ni], acc[mi][ni], 0, 0, 0);
            acc[mi][ni] = __builtin_amdgcn_mfma_f32_16x16x32_f16(Al[mi], Bh[ni], acc[mi][ni], 0, 0, 0);
            acc[mi][ni] = __builtin_amdgcn_mfma_f32_16x16x32_f16(Ah[mi], Bl[ni], acc[mi][ni], 0, 0, 0);
          }
      }
    }
    const float SC = 1.0f / 65536.0f;
    float* dst = (by < 4) ? out : Pg;  // PRE_mlp -> d_out, PRE_gate -> ws
    const float* bias = (by < 4) ? bm : bg;
#pragma unroll
    for (int ni = 0; ni < 4; ni++) {
      int oc = (by < 4) ? ncol[ni] : ncol[ni] - 512;
      float bi = bias[oc];
#pragma unroll
      for (int mi = 0; mi < 4; mi++) {
        int rowb = bt0 + wm * 64 + mi * 16 + kg * 4;
#pragma unroll
        for (int rr = 0; rr < 4; rr++)
          dst[(size_t)(rowb + rr) * Dq + oc] = fmaf(acc[mi][ni][rr], SC, bi);
      }
    }
  }

  // ---- publish: all stores visible, then bump the band counter ----
  __threadfence();
  __syncthreads();
  if (tid == 0) {
    __hip_atomic_fetch_add(&done[bat * 16 + band], 1, __ATOMIC_RELEASE,
                           __HIP_MEMORY_SCOPE_AGENT);
  }
}

// ---------------------------------------------------------------------------
// f32 fallback (ws too small) — R1-verified serial GEMM + 4-wave scan.
// ---------------------------------------------------------------------------
__global__ __launch_bounds__(256) void gemm_pre(
    const float* __restrict__ O, const float* __restrict__ Wm,
    const float* __restrict__ Wg, const float* __restrict__ bm,
    const float* __restrict__ bg, float* __restrict__ Pm,
    float* __restrict__ Pg, float* __restrict__ Gm, int mode) {
  const int BM = 128, BN = 128, BK = 16;
  __shared__ float As[BK][132];
  __shared__ float Bs[BK][132];
  int tidx = threadIdx.x;
  int bt0 = blockIdx.x * BM;
  int b = bt0 / Tq;
  int t0 = bt0 % Tq;
  int n0 = blockIdx.y * BN;
  int K = mode ? Dq : 5 * Dq;
  int tx = tidx % 16, ty = tidx / 16, lr = tidx >> 2, lc = (tidx & 3) * 4;
  float acc[8][8];
#pragma unroll
  for (int i = 0; i < 8; i++)
#pragma unroll
    for (int j = 0; j < 8; j++) acc[i][j] = 0.f;
  for (int kb = 0; kb < K; kb += BK) {
#pragma unroll
    for (int h = 0; h < 2; h++) {
      int m = lr + h * 64;
      int t = t0 + m;
      float4 av;
      if (mode == 0) {
        int j = kb >> 9;
        int kcol = (kb & 511) + lc;
        int sh = 2 - t; if (sh < 0) sh = 0;
        int r = t - 2 + j + sh;
        int hi = t + 2; if (hi > Tq - 1) hi = Tq - 1;
        int lo2 = t - 2; if (lo2 < 0) lo2 = 0;
        int nv = hi - lo2 + 1;
        if (j < nv) av = *reinterpret_cast<const float4*>(O + ((size_t)b * Tq + r) * Dq + kcol);
        else av = make_float4(0.f, 0.f, 0.f, 0.f);
      } else {
        av = *reinterpret_cast<const float4*>(O + ((size_t)b * Tq + t) * Dq + kb + lc);
      }
      As[lc + 0][m] = av.x; As[lc + 1][m] = av.y;
      As[lc + 2][m] = av.z; As[lc + 3][m] = av.w;
    }
#pragma unroll
    for (int h = 0; h < 2; h++) {
      int n = lr + h * 64;
      int gn = n0 + n;
      const float* wrow;
      int col;
      if (mode == 0) {
        if (gn < 512) { wrow = Wm + (size_t)gn * 2560; col = kb + lc; }
        else          { wrow = Wg + (size_t)(gn - 512) * 3072; col = kb + lc; }
      } else {
        wrow = Wg + (size_t)gn * 3072; col = 2560 + kb + lc;
      }
      float4 bv = *reinterpret_cast<const float4*>(wrow + col);
      Bs[lc + 0][n] = bv.x; Bs[lc + 1][n] = bv.y;
      Bs[lc + 2][n] = bv.z; Bs[lc + 3][n] = bv.w;
    }
    __syncthreads();
#pragma unroll
    for (int kk = 0; kk < BK; kk++) {
      float a[8], bb[8];
      float4 a0 = *reinterpret_cast<float4*>(&As[kk][ty * 8]);
      float4 a1 = *reinterpret_cast<float4*>(&As[kk][ty * 8 + 4]);
      float4 b0 = *reinterpret_cast<float4*>(&Bs[kk][tx * 8]);
      float4 b1 = *reinterpret_cast<float4*>(&Bs[kk][tx * 8 + 4]);
      a[0]=a0.x; a[1]=a0.y; a[2]=a0.z; a[3]=a0.w; a[4]=a1.x; a[5]=a1.y; a[6]=a1.z; a[7]=a1.w;
      bb[0]=b0.x; bb[1]=b0.y; bb[2]=b0.z; bb[3]=b0.w; bb[4]=b1.x; bb[5]=b1.y; bb[6]=b1.z; bb[7]=b1.w;
#pragma unroll
      for (int i = 0; i < 8; i++)
#pragma unroll
        for (int j = 0; j < 8; j++) acc[i][j] = fmaf(a[i], bb[j], acc[i][j]);
    }
    __syncthreads();
  }
  int gn = n0 + tx * 8;
  float bias[8];
  float* dstbase;
  int coloff;
  if (mode == 0) {
    if (gn < 512) {
#pragma unroll
      for (int j = 0; j < 8; j++) bias[j] = bm[gn + j];
      dstbase = Pm; coloff = gn;
    } else {
#pragma unroll
      for (int j = 0; j < 8; j++) bias[j] = bg[gn - 512 + j];
      dstbase = Pg; coloff = gn - 512;
    }
  } else {
#pragma unroll
    for (int j = 0; j < 8; j++) bias[j] = 0.f;
    dstbase = Gm; coloff = gn;
  }
#pragma unroll
  for (int i = 0; i < 8; i++) {
    int bt = bt0 + ty * 8 + i;
    float4 v0 = make_float4(acc[i][0] + bias[0], acc[i][1] + bias[1],
                            acc[i][2] + bias[2], acc[i][3] + bias[3]);
    float4 v1 = make_float4(acc[i][4] + bias[4], acc[i][5] + bias[5],
                            acc[i][6] + bias[6], acc[i][7] + bias[7]);
    float4* d = reinterpret_cast<float4*>(dstbase + (size_t)bt * Dq + coloff);
    d[0] = v0;
    d[1] = v1;
  }
}

// Fallback serial 4-wave scan (done[] pre-filled to 12 so gates are no-ops).
__global__ __launch_bounds__(256, 1) void scan_only(
    const float* __restrict__ O, const float* __restrict__ Gm,
    const float* __restrict__ Pg, const float* __restrict__ Pm,
    float* __restrict__ out, int* __restrict__ done) {
  __shared__ __align__(16) float red[2][5][4];
  int b = blockIdx.x;
  int tid = threadIdx.x;
  int w = tid >> 6;
  int lane = tid & 63;
  int dbase = w * 128 + lane * 2;
  int bb = b * 16;
  const float* ob  = O  + (size_t)b * Tq * Dq;
  const float* Gb  = Gm + (size_t)b * Tq * Dq;
  const float* Pgb = Pg + (size_t)b * Tq * Dq;
  const float* pmb = Pm + (size_t)b * Tq * Dq;
  float* po = out + (size_t)b * Tq * Dq;
  int bandReady = 15;

  float2 ow[8], gw[8], pm[8], pg[8];
  float2 st = make_float2(0.f, 0.f);
#pragma unroll
  for (int r = 0; r < 5; r++) {
    ow[r] = *(const float2*)(ob  + (size_t)r * Dq + dbase);
    gw[r] = *(const float2*)(Gb  + (size_t)r * Dq + dbase);
    pm[r] = *(const float2*)(pmb + (size_t)r * Dq + dbase);
    pg[r] = *(const float2*)(Pgb + (size_t)r * Dq + dbase);
  }
#define SS(t_, m3_, m4_, A,B,C,D,E, SL_, LW_)                                  \
  scan_step4<A,B,C,D,E, SL_, LW_>(t_, m3_, m4_, lane, w, dbase, ob, Gb,        \
      Pgb, pmb, po, red, done, bb, bandReady, ow, gw, pm, pg, st)
  SS(0, 0.f, 0.f, 0,1,2,3,4, 0, 5);
  SS(1, 1.f, 0.f, 0,1,2,3,4, 1, 6);
  for (int tb = 2; tb <= 2034; tb += 8) {
    SS(tb+0, 1.f, 1.f, 0,1,2,3,4, 2, 7);
    SS(tb+1, 1.f, 1.f, 1,2,3,4,5, 3, 0);
    SS(tb+2, 1.f, 1.f, 2,3,4,5,6, 4, 1);
    SS(tb+3, 1.f, 1.f, 3,4,5,6,7, 5, 2);
    SS(tb+4, 1.f, 1.f, 4,5,6,7,0, 6, 3);
    SS(tb+5, 1.f, 1.f, 5,6,7,0,1, 7, 4);
    SS(tb+6, 1.f, 1.f, 6,7,0,1,2, 0, 5);
    SS(tb+7, 1.f, 1.f, 7,0,1,2,3, 1, 6);
  }
  SS(2042, 1.f, 1.f, 0,1,2,3,4, 2, 7);
  SS(2043, 1.f, 1.f, 1,2,3,4,5, 3, 0);
  SS(2044, 1.f, 1.f, 2,3,4,5,6, 4, 1);
  SS(2045, 1.f, 1.f, 3,4,5,6,7, 5, 2);
  SS(2046, 1.f, 0.f, 4,5,6,7,0, 6, 3);
  SS(2047, 0.f, 0.f, 5,6,7,0,1, 7, 4);
#undef SS
}

extern "C" void kernel_launch(void* const* d_in, const int* in_sizes, int n_in,
                              void* d_out, int out_size, void* d_ws, size_t ws_size,
                              hipStream_t stream) {
  const float* O  = (const float*)d_in[0];
  const float* Wm = (const float*)d_in[1];
  const float* bm = (const float*)d_in[2];
  const float* Wg = (const float*)d_in[3];
  const float* bg = (const float*)d_in[4];
  float* out = (float*)d_out;

  const size_t NTOT = (size_t)Bq * Tq * Dq;   // 8.39M
  const size_t NWM = 512 * 2560, NWG = 512 * 3072;
  float* Pg = (float*)d_ws;
  float* Gm = Pg + NTOT;
  ushort* WMH = (ushort*)(Gm + NTOT);
  ushort* WML = WMH + NWM;
  ushort* WGH = WML + NWM;
  ushort* WGL = WGH + NWG;
  int* done = (int*)(WGL + NWG);              // 128 ints

  size_t need = 2 * NTOT * 4 + 2 * (NWM + NWG) * 2 + 128 * 4;  // ~78.5 MB
  if (ws_size >= need) {
    hipMemsetAsync(done, 0, 128 * 4, stream);
    cvt_f16split<<<dim3((NWM / 8 + 255) / 256), dim3(256), 0, stream>>>(Wm, WMH, WML, NWM / 8);
    cvt_f16split<<<dim3((NWG / 8 + 255) / 256), dim3(256), 0, stream>>>(Wg, WGH, WGL, NWG / 8);
    fused_kernel<<<dim3(8 + 16 * 96), dim3(256), 0, stream>>>(
        O, WMH, WML, WGH, WGL, bm, bg, Pg, Gm, out, done);
  } else {
    bool sep = ws_size >= (size_t)(3 * NTOT * 4 + 128 * 4);
    float* Pm = sep ? (Gm + NTOT) : out;
    int* done2 = sep ? (int*)(Pm + NTOT) : (int*)(Gm + NTOT);
    hipMemsetAsync(done2, 12, 128 * 4, stream);  // every byte 12 -> >= 12
    gemm_pre<<<dim3(128, 8), dim3(256), 0, stream>>>(O, Wm, Wg, bm, bg, Pm, Pg, Gm, 0);
    gemm_pre<<<dim3(128, 4), dim3(256), 0, stream>>>(O, Wm, Wg, bm, bg, Pm, Pg, Gm, 1);
    scan_only<<<dim3(Bq), dim3(256), 0, stream>>>(O, Gm, Pg, Pm, out, done2);
  }
}